// Round 15
// baseline (210.236 us; speedup 1.0000x reference)
//
#include <hip/hip_runtime.h>
#include <hip/hip_bf16.h>
#include <math.h>

#define NDOM 6
#define BB 4
#define TT 1024
#define DD 768
#define PP 3
#define HH 2
#define DHH 32
#define II 64
#define SS (PP*TT)        // 3072
#define NROW (NDOM*BB*TT) // 24576
#define NKVROW (NDOM*BB*SS)
#define NSPLIT 8
#define NITER (SS/NSPLIT/64)   // 6
#define NKVB (NKVROW/128) // 576
#define NQB  (NROW/128)   // 192
#define LNEPS 1e-5f

typedef unsigned int uint;
typedef uint  u32x4  __attribute__((ext_vector_type(4)));
typedef int   i32x2  __attribute__((ext_vector_type(2)));
typedef float f32x2  __attribute__((ext_vector_type(2)));
typedef float f32x4  __attribute__((ext_vector_type(4)));
typedef float f32x16 __attribute__((ext_vector_type(16)));
typedef __bf16 bf16x8 __attribute__((ext_vector_type(8)));

// D = A(32x16) * B(16x32) + C.  A row = lane&31, k = (lane>>5)*8+j.
// B col = lane&31, k = (lane>>5)*8+j.  D: col = lane&31, row=(r&3)+8*(r>>2)+4*(lane>>5).
__device__ __forceinline__ f32x16 mfma32(u32x4 a, u32x4 b, f32x16 c) {
  return __builtin_amdgcn_mfma_f32_32x32x16_bf16(
      __builtin_bit_cast(bf16x8, a), __builtin_bit_cast(bf16x8, b), c, 0, 0, 0);
}

__device__ __forceinline__ uint pkbf(float a, float b) {
  union { __bf16 h[2]; uint u; } v;
  v.h[0] = (__bf16)a; v.h[1] = (__bf16)b;
  return v.u;
}
__device__ __forceinline__ float b2f(uint u16) {
  union { uint i; float f; } v; v.i = u16 << 16; return v.f;
}

// x gets {a_lo | partner's b}, y gets {partner's a | b}  (32-lane halves)
__device__ __forceinline__ void plswap(uint a, uint b, uint& x, uint& y) {
#if __has_builtin(__builtin_amdgcn_permlane32_swap)
  i32x2 r = __builtin_amdgcn_permlane32_swap((int)a, (int)b, false, false);
  x = (uint)r.x; y = (uint)r.y;
#else
  uint sa = __shfl_xor(a, 32), sb = __shfl_xor(b, 32);
  bool h1 = (threadIdx.x & 32) != 0;
  x = h1 ? sb : a;
  y = h1 ? b : sa;
#endif
}

// async global->LDS, 16B per lane.  LDS dest = wave-uniform base + lane*16.
#if __has_builtin(__builtin_amdgcn_global_load_lds)
#define HAS_GLL 1
typedef __attribute__((address_space(3))) uint lds_u32;
typedef __attribute__((address_space(1))) uint glb_u32;
__device__ __forceinline__ void gll16(const void* src, void* lds_base) {
  __builtin_amdgcn_global_load_lds((const glb_u32*)src, (lds_u32*)lds_base, 16, 0, 0);
}
#else
#define HAS_GLL 0
#endif

// ---------------------------------------------------------------------------
// Prep: bf16 transposed weights (B-side pre-XOR-swizzled within each 64-k
// chunk so a LINEAR global_load_lds yields LDS[c][u] = B[c][u^(c&7)]),
// Bo row-major, exp2-domain mask bias.
// ---------------------------------------------------------------------------
__global__ __launch_bounds__(256) void prep_kernel(
    const int* __restrict__ mask, const float* __restrict__ Wk,
    const float* __restrict__ Wv, const float* __restrict__ Wq,
    const float* __restrict__ Wo,
    __hip_bfloat16* __restrict__ Bkv, __hip_bfloat16* __restrict__ Bq,
    __hip_bfloat16* __restrict__ Bo, float* __restrict__ bias2)
{
  int i = blockIdx.x * 256 + threadIdx.x;
  const int N1 = 128 * 768;          // Bkv (swizzled)
  const int N2 = NDOM * 64 * 768;    // Bq  (swizzled)
  const int N3 = NDOM * 768 * 64;    // Bo
  if (i < N1) {
    int c = i / 768, kd = i % 768;
    int e = kd & 7, ud = (kd >> 3) & 7, kk = kd >> 6;
    int k = (kk << 6) + ((ud ^ (c & 7)) << 3) + e;
    float v = (c < 64) ? Wk[k * 64 + c] : Wv[k * 64 + (c - 64)];
    Bkv[i] = __float2bfloat16(v);
  } else if (i < N1 + N2) {
    int j = i - N1;
    int n = j / (64 * 768);
    int rem = j % (64 * 768);
    int c = rem / 768, kd = rem % 768;
    int e = kd & 7, ud = (kd >> 3) & 7, kk = kd >> 6;
    int k = (kk << 6) + ((ud ^ (c & 7)) << 3) + e;
    Bq[j] = __float2bfloat16(Wq[((size_t)n * 768 + k) * 64 + c]);
  } else if (i < N1 + N2 + N3) {
    int j = i - N1 - N2;
    int n = j / (768 * 64);
    int rem = j % (768 * 64);
    int d = rem / 64, k = rem % 64;
    Bo[j] = __float2bfloat16(Wo[((size_t)n * 64 + k) * 768 + d]);
  } else if (i < N1 + N2 + N3 + BB * SS) {
    int j = i - N1 - N2 - N3;
    int b = j / SS, s = j % SS;
    bias2[j] = (1.0f - (float)mask[b * TT + (s & (TT - 1))]) * (-14426.950408889634f);
  }
}

// ---------------------------------------------------------------------------
// Fused Q + KV projection GEMM, m97 structure: BM=128, BK=64, BOTH operands
// staged per chunk via global_load_lds (contiguous 1KB/instr), single LDS
// buffer, sync -> vmem-free compute (ds_read + cvt_pk + MFMA) -> sync.
// (proven round 14: best of 7 qkv structures — do not restructure)
// ---------------------------------------------------------------------------
__global__ __launch_bounds__(256) void qkv_gemm_kernel(
    const float* __restrict__ x, const float* __restrict__ hist,
    const __hip_bfloat16* __restrict__ Bkv, const __hip_bfloat16* __restrict__ Bq,
    __hip_bfloat16* __restrict__ Qo, __hip_bfloat16* __restrict__ Kh,
    __hip_bfloat16* __restrict__ Vt2)
{
  __shared__ float As[128 * 64];            // 32 KB
  __shared__ __hip_bfloat16 Bs[128 * 64];   // 16 KB
  const int tid = threadIdx.x;
  const int lane = tid & 63, w = tid >> 6;
  const int cl = lane & 31, hi = lane >> 5;

  const bool isKV = blockIdx.x < NKVB;
  const float* Asrc;
  int nb = 0, s0 = 0, n = 0, brow = 0;
  if (isKV) {
    brow = blockIdx.x * 128;
    nb = brow / SS; n = nb >> 2;
    int b = nb & 3;
    s0 = brow % SS;
    int p = s0 / TT, t0 = s0 % TT;          // 128 | 1024: block stays in one p
    Asrc = hist + (((size_t)(p * NDOM + n) * BB + b) * TT + t0) * 768;
  } else {
    brow = (blockIdx.x - NKVB) * 128;
    n = brow >> 12;
    Asrc = x + (size_t)brow * 768;
  }
  const __hip_bfloat16* Bsrc = isKV ? Bkv : (Bq + (size_t)n * 64 * 768);
  const int BROWS = isKV ? 128 : 64;        // B panel rows (cols of output)
  const int NACC = isKV ? 4 : 2;

  f32x16 acc[4] = {};

  const int lrow16 = lane >> 4, lslot16 = lane & 15;   // A staging decode
  const int lrow8  = lane >> 3, lslot8  = lane & 7;    // B staging decode

  for (int kk = 0; kk < 12; ++kk) {
    // ---- stage A: wave w stages rows [w*32, w*32+32), 8 gll x 4 rows ----
#pragma unroll
    for (int j = 0; j < 8; ++j) {
      int row0 = w * 32 + j * 4;
      int row = row0 + lrow16;
      int gs = lslot16 ^ (row & 15);
      const float* src = Asrc + (size_t)row * 768 + kk * 64 + gs * 4;
#if HAS_GLL
      gll16(src, &As[row0 * 64]);
#else
      *(f32x4*)(&As[row0 * 64] + lane * 4) = *(const f32x4*)src;
#endif
    }
    // ---- stage B: BROWS rows split over 4 waves, gll x 8 rows each ----
    {
      int perw = BROWS / 4;                 // 32 (KV) or 16 (Q)
#pragma unroll
      for (int j = 0; j < 4; ++j) {
        if (j * 8 < perw) {
          int c0 = w * perw + j * 8;
          int c = c0 + lrow8;
          const __hip_bfloat16* src = Bsrc + (size_t)c * 768 + kk * 64 + lslot8 * 8;
#if HAS_GLL
          gll16(src, &Bs[c0 * 64]);
#else
          *(u32x4*)(&Bs[c0 * 64] + lane * 8) = *(const u32x4*)src;
#endif
        }
      }
    }
    __syncthreads();   // drains vmcnt + barrier (m97 semantics)

    // ---- compute chunk kk (vmem-free) ----
    {
      const int row = w * 32 + cl;
#pragma unroll
      for (int ks = 0; ks < 4; ++ks) {
        int t = ks * 4 + hi * 2;
        f32x4 a0 = *(const f32x4*)&As[row * 64 + ((t       ^ (row & 15)) * 4)];
        f32x4 a1 = *(const f32x4*)&As[row * 64 + (((t + 1) ^ (row & 15)) * 4)];
        u32x4 a = {pkbf(a0.x, a0.y), pkbf(a0.z, a0.w), pkbf(a1.x, a1.y), pkbf(a1.z, a1.w)};
        int u0 = ks * 2 + hi;
#pragma unroll
        for (int g = 0; g < 4; ++g) {
          if (g < NACC) {
            int c = g * 32 + cl;
            u32x4 b = *(const u32x4*)&Bs[c * 64 + ((u0 ^ (c & 7)) * 8)];
            acc[g] = mfma32(a, b, acc[g]);
          }
        }
      }
    }
    __syncthreads();   // protect single buffer before next stage
  }

  if (isKV) {
    // K store: acc0/acc1 = K heads 0/1 (head-split rows of 64B)
    {
      const size_t base0 = (size_t)(nb * 2 + 0) * SS;
      const size_t base1 = (size_t)(nb * 2 + 1) * SS;
#pragma unroll
      for (int r = 0; r < 16; ++r) {
        int rl = (r & 3) + 8 * (r >> 2) + 4 * hi;
        int s  = s0 + w * 32 + rl;
        Kh[(base0 + s) * 32 + cl] = __float2bfloat16(acc[0][r]);
        Kh[(base1 + s) * 32 + cl] = __float2bfloat16(acc[1][r]);
      }
    }
    // V store: acc2/acc3 = V heads 0/1 -> Vt2[nb][h][sb][c][8]
#pragma unroll
    for (int k = 0; k < 4; ++k) {
      int sb = (s0 + w * 32 + 8 * k) >> 3;
      size_t A0 = (((size_t)(nb * 2 + 0) * (SS / 8) + sb) * 32 + cl) * 8 + 4 * hi;
      size_t A1 = (((size_t)(nb * 2 + 1) * (SS / 8) + sb) * 32 + cl) * 8 + 4 * hi;
      *(uint2*)(Vt2 + A0) = uint2{pkbf(acc[2][4*k], acc[2][4*k+1]), pkbf(acc[2][4*k+2], acc[2][4*k+3])};
      *(uint2*)(Vt2 + A1) = uint2{pkbf(acc[3][4*k], acc[3][4*k+1]), pkbf(acc[3][4*k+2], acc[3][4*k+3])};
    }
  } else {
#pragma unroll
    for (int r = 0; r < 16; ++r) {
      int rl = (r & 3) + 8 * (r >> 2) + 4 * hi;
      size_t rb = (size_t)(brow + w * 32 + rl) * 64;
      Qo[rb + cl]      = __float2bfloat16(acc[0][r]);
      Qo[rb + 32 + cl] = __float2bfloat16(acc[1][r]);
    }
  }
}

// ---------------------------------------------------------------------------
// Flash attention, split-S by 8 (3072 blocks -> 8 blocks/CU = 32 waves/CU,
// occupancy cap).  Block = 4 waves sharing one (n,b,h,split): wave w owns
// q-tile tq*4+w; all waves stream the SAME K/V tiles in lockstep (raw
// s_barrier per iter, no LDS) -> L1 broadcast hits.
// ---------------------------------------------------------------------------
struct KV { u32x4 k0, k1, k2, k3, v0, v1, v2, v3; };

__global__ __launch_bounds__(256) void attn_kernel(
    const __hip_bfloat16* __restrict__ Q, const __hip_bfloat16* __restrict__ Kh,
    const __hip_bfloat16* __restrict__ Vt2, const float* __restrict__ bias2,
    __hip_bfloat16* __restrict__ Op, float* __restrict__ Mp, float* __restrict__ Lp)
{
  const int tid = threadIdx.x;
  const int lane = tid & 63, w = tid >> 6;
  const int cl = lane & 31, hi = lane >> 5;
  const int bid = blockIdx.x;
  const int g = bid % 48;            // (n,b,h) group -> fixed XCD (48 % 8 == 0)
  const int rest = bid / 48;         // 0..63
  const int sp = rest >> 3;          // split 0..7
  const int tq = rest & 7;           // q super-tile 0..7
  const int qtile = tq * 4 + w;      // 0..31
  const int h = g & 1, nb = g >> 1;
  const int b = nb & 3;
  const int qrow = nb * TT + qtile * 32;
  const int sbase = sp * (SS / NSPLIT);   // 384 keys per split

  const __hip_bfloat16* Qp = Q + (size_t)(qrow + cl) * 64 + h * 32 + hi * 8;
  u32x4 qf0 = *(const u32x4*)Qp;
  u32x4 qf1 = *(const u32x4*)(Qp + 16);

  const __hip_bfloat16* Kp = Kh + ((size_t)(nb * 2 + h) * SS + sbase) * 32;
  const __hip_bfloat16* Vp = Vt2 + (size_t)(nb * 2 + h) * SS * 32 + (size_t)sbase * 32;
  const float* Bp = bias2 + b * SS + sbase + hi * 4;

  const float scale2 = 0.17677669529663687f * 1.4426950408889634f;
  const f32x2 sc2 = {scale2, scale2};

  f32x16 ot = {};
  float m = -1e30f, lsum = 0.f;

  auto loadKV = [&](int it) {
    KV t;
    const __hip_bfloat16* kp = Kp + (size_t)it * 64 * 32;
    t.k0 = *(const u32x4*)(kp + cl * 32 + hi * 8);
    t.k1 = *(const u32x4*)(kp + cl * 32 + 16 + hi * 8);
    t.k2 = *(const u32x4*)(kp + 1024 + cl * 32 + hi * 8);
    t.k3 = *(const u32x4*)(kp + 1024 + cl * 32 + 16 + hi * 8);
    const __hip_bfloat16* vp = Vp + (size_t)it * 64 * 32;
    t.v0 = *(const u32x4*)(vp + ((0 * 2 + hi) * 32 + cl) * 8);
    t.v1 = *(const u32x4*)(vp + ((1 * 2 + hi) * 32 + cl) * 8);
    t.v2 = *(const u32x4*)(vp + ((2 * 2 + hi) * 32 + cl) * 8);
    t.v3 = *(const u32x4*)(vp + ((3 * 2 + hi) * 32 + cl) * 8);
    return t;
  };

  auto compute = [&](const KV& t, int it) {
    f32x16 pz0 = {}, pz1 = {};
    pz0 = mfma32(t.k0, qf0, pz0);
    pz0 = mfma32(t.k1, qf1, pz0);
    pz1 = mfma32(t.k2, qf0, pz1);
    pz1 = mfma32(t.k3, qf1, pz1);
    const float* bp = Bp + it * 64;
    f32x4 b4[8];
#pragma unroll
    for (int q = 0; q < 8; ++q) b4[q] = *(const f32x4*)(bp + 8 * q);
    f32x2 p2[16];
#pragma unroll
    for (int i = 0; i < 8; ++i) {
      f32x4 bq0 = b4[i >> 1];
      f32x4 bq1 = b4[4 + (i >> 1)];
      f32x2 bv0 = (i & 1) ? f32x2{bq0.z, bq0.w} : f32x2{bq0.x, bq0.y};
      f32x2 bv1 = (i & 1) ? f32x2{bq1.z, bq1.w} : f32x2{bq1.x, bq1.y};
      p2[i]     = f32x2{pz0[2*i], pz0[2*i+1]} * sc2 + bv0;
      p2[8 + i] = f32x2{pz1[2*i], pz1[2*i+1]} * sc2 + bv1;
    }
    f32x2 mx = p2[0];
#pragma unroll
    for (int i = 1; i < 16; ++i) {
      mx.x = fmaxf(mx.x, p2[i].x);
      mx.y = fmaxf(mx.y, p2[i].y);
    }
    float tm = fmaxf(mx.x, mx.y);
    tm = fmaxf(tm, __shfl_xor(tm, 32));
    if (!__all(tm - m <= 8.f)) {       // defer-max
      float mn = fmaxf(m, tm);
      float f = exp2f(m - mn);
#pragma unroll
      for (int i = 0; i < 16; ++i) ot[i] *= f;
      lsum *= f;
      m = mn;
    }
    const f32x2 m2 = {m, m};
    f32x2 s2 = {0.f, 0.f};
#pragma unroll
    for (int i = 0; i < 16; ++i) {
      f32x2 d = p2[i] - m2;
      f32x2 e = {exp2f(d.x), exp2f(d.y)};
      p2[i] = e;
      s2 += e;
    }
    float ts = s2.x + s2.y;
    ts += __shfl_xor(ts, 32);
    lsum += ts;
    // P -> bf16 B-frags via permlane32_swap
    uint cv[16];
#pragma unroll
    for (int i = 0; i < 16; ++i) cv[i] = pkbf(p2[i].x, p2[i].y);
    u32x4 pf0, pf1, pf2, pf3;
    {
      uint x0, y0, x1, y1;
      plswap(cv[0], cv[2],  x0, y0); plswap(cv[1], cv[3],  x1, y1);
      pf0 = u32x4{x0, x1, y0, y1};
      plswap(cv[4], cv[6],  x0, y0); plswap(cv[5], cv[7],  x1, y1);
      pf1 = u32x4{x0, x1, y0, y1};
      plswap(cv[8], cv[10], x0, y0); plswap(cv[9], cv[11], x1, y1);
      pf2 = u32x4{x0, x1, y0, y1};
      plswap(cv[12], cv[14], x0, y0); plswap(cv[13], cv[15], x1, y1);
      pf3 = u32x4{x0, x1, y0, y1};
    }
    ot = mfma32(t.v0, pf0, ot);
    ot = mfma32(t.v1, pf1, ot);
    ot = mfma32(t.v2, pf2, ot);
    ot = mfma32(t.v3, pf3, ot);
  };

  KV cur = loadKV(0);
#pragma unroll 1
  for (int it = 0; it < NITER; ++it) {
    KV nxt = loadKV(it + 1 < NITER ? it + 1 : NITER - 1);
    compute(cur, it);
    cur = nxt;
    __builtin_amdgcn_s_barrier();   // keep the 4 waves' K/V streams in lockstep (L1 reuse)
  }

  // store unnormalized O^T partial (bf16) + m/l
  __hip_bfloat16* op = Op + ((size_t)sp * NROW + qrow + cl) * 64 + h * 32 + 4 * hi;
#pragma unroll
  for (int k = 0; k < 4; ++k) {
    uint2 wv = {pkbf(ot[4*k], ot[4*k+1]), pkbf(ot[4*k+2], ot[4*k+3])};
    *(uint2*)(op + 8 * k) = wv;
  }
  if (lane < 32) {
    int mi = ((sp * 24 + nb) * 2 + h) * TT + qtile * 32 + cl;
    Mp[mi] = m;
    Lp[mi] = lsum;
  }
}

// ---------------------------------------------------------------------------
// Fused split-combine + out-projection (MFMA) + residual + LayerNorm.
// Block 256 = 4 waves, 32 rows; wave w owns cols [w*192, +192).
// ---------------------------------------------------------------------------
__global__ __launch_bounds__(256) void oproj_ln_kernel(
    const float* __restrict__ x, const __hip_bfloat16* __restrict__ Op,
    const float* __restrict__ Mp, const float* __restrict__ Lp,
    const __hip_bfloat16* __restrict__ Bo, const float* __restrict__ gamma,
    const float* __restrict__ beta, float* __restrict__ out)
{
  __shared__ float red[4][32][2];
  __shared__ float redf[32][2];
  const int tid = threadIdx.x;
  const int lane = tid & 63, w = tid >> 6;
  const int cl = lane & 31, hi = lane >> 5;
  const int row0 = blockIdx.x * 32;
  const int n = row0 >> 12;
  const int nb = row0 >> 10;
  const int trow = (row0 & 1023) + cl;
  const int MLS = 24 * 2 * TT;

  // combine weights per head
  float wsp[2][NSPLIT];
#pragma unroll
  for (int h = 0; h < 2; ++h) {
    int mi = (nb * 2 + h) * TT + trow;
    float mv[NSPLIT], lv[NSPLIT];
#pragma unroll
    for (int sp = 0; sp < NSPLIT; ++sp) { mv[sp] = Mp[mi + sp * MLS]; lv[sp] = Lp[mi + sp * MLS]; }
    float ms = mv[0];
#pragma unroll
    for (int sp = 1; sp < NSPLIT; ++sp) ms = fmaxf(ms, mv[sp]);
    float den = 0.f;
#pragma unroll
    for (int sp = 0; sp < NSPLIT; ++sp) { wsp[h][sp] = exp2f(mv[sp] - ms); den = fmaf(lv[sp], wsp[h][sp], den); }
    float inv = 1.0f / den;
#pragma unroll
    for (int sp = 0; sp < NSPLIT; ++sp) wsp[h][sp] *= inv;
  }

  // A-frags: combine partials
  u32x4 af[4];
#pragma unroll
  for (int ks = 0; ks < 4; ++ks) {
    int h = ks >> 1;
    size_t off = (size_t)(row0 + cl) * 64 + ks * 16 + hi * 8;
    f32x2 s0 = {}, s1 = {}, s2 = {}, s3 = {};
#pragma unroll
    for (int sp = 0; sp < NSPLIT; ++sp) {
      u32x4 v = *(const u32x4*)(Op + (size_t)sp * NROW * 64 + off);
      float wv = wsp[h][sp];
      s0 += f32x2{b2f(v[0] & 0xffffu), b2f(v[0] >> 16)} * wv;
      s1 += f32x2{b2f(v[1] & 0xffffu), b2f(v[1] >> 16)} * wv;
      s2 += f32x2{b2f(v[2] & 0xffffu), b2f(v[2] >> 16)} * wv;
      s3 += f32x2{b2f(v[3] & 0xffffu), b2f(v[3] >> 16)} * wv;
    }
    af[ks] = u32x4{pkbf(s0.x, s0.y), pkbf(s1.x, s1.y), pkbf(s2.x, s2.y), pkbf(s3.x, s3.y)};
  }

  const __hip_bfloat16* Bp = Bo + ((size_t)n * 768 + w * 192 + cl) * 64 + hi * 8;
  f32x16 acc[6] = {};
#pragma unroll
  for (int ks = 0; ks < 4; ++ks) {
#pragma unroll
    for (int t = 0; t < 6; ++t) {
      u32x4 bb = *(const u32x4*)(Bp + (size_t)(t * 32) * 64 + ks * 16);
      acc[t] = mfma32(af[ks], bb, acc[t]);
    }
  }

  float s1[16], s2[16];
#pragma unroll
  for (int r = 0; r < 16; ++r) { s1[r] = 0.f; s2[r] = 0.f; }
#pragma unroll
  for (int t = 0; t < 6; ++t) {
#pragma unroll
    for (int r = 0; r < 16; ++r) {
      int R = (r & 3) + 8 * (r >> 2) + 4 * hi;
      int col = w * 192 + t * 32 + cl;
      float y = acc[t][r] + x[(size_t)(row0 + R) * 768 + col];
      acc[t][r] = y;
      s1[r] += y;
      s2[r] = fmaf(y, y, s2[r]);
    }
  }
#pragma unroll
  for (int r = 0; r < 16; ++r) {
#pragma unroll
    for (int off = 1; off < 32; off <<= 1) {
      s1[r] += __shfl_xor(s1[r], off);
      s2[r] += __shfl_xor(s2[r], off);
    }
  }
  if (cl == 0) {
#pragma unroll
    for (int r = 0; r < 16; ++r) {
      int R = (r & 3) + 8 * (r >> 2) + 4 * hi;
      red[w][R][0] = s1[r];
      red[w][R][1] = s2[r];
    }
  }
  __syncthreads();
  if (tid < 64) {
    int R = tid & 31, st = tid >> 5;
    redf[R][st] = red[0][R][st] + red[1][R][st] + red[2][R][st] + red[3][R][st];
  }
  __syncthreads();

  float gv[6], bv[6];
#pragma unroll
  for (int t = 0; t < 6; ++t) {
    int col = w * 192 + t * 32 + cl;
    gv[t] = gamma[n * 768 + col];
    bv[t] = beta[n * 768 + col];
  }
#pragma unroll
  for (int r = 0; r < 16; ++r) {
    int R = (r & 3) + 8 * (r >> 2) + 4 * hi;
    float mu = redf[R][0] * (1.0f / 768.0f);
    float var = redf[R][1] * (1.0f / 768.0f) - mu * mu;
    float rs = rsqrtf(var + LNEPS);
#pragma unroll
    for (int t = 0; t < 6; ++t) {
      int col = w * 192 + t * 32 + cl;
      out[(size_t)(row0 + R) * 768 + col] = (acc[t][r] - mu) * rs * gv[t] + bv[t];
    }
  }
}

// ---------------------------------------------------------------------------
extern "C" void kernel_launch(void* const* d_in, const int* in_sizes, int n_in,
                              void* d_out, int out_size, void* d_ws, size_t ws_size,
                              hipStream_t stream) {
  const float* x     = (const float*)d_in[0];
  const float* hist  = (const float*)d_in[1];
  const int*   mask  = (const int*)d_in[2];
  const float* Wq    = (const float*)d_in[3];
  const float* Wk    = (const float*)d_in[4];
  const float* Wv    = (const float*)d_in[5];
  const float* Wo    = (const float*)d_in[6];
  const float* gamma = (const float*)d_in[7];
  const float* beta  = (const float*)d_in[8];
  float* out = (float*)d_out;

  char* ws = (char*)d_ws;
  __hip_bfloat16* Qb  = (__hip_bfloat16*)ws;  ws += (size_t)NROW * II * 2;
  __hip_bfloat16* Kh  = (__hip_bfloat16*)ws;  ws += (size_t)NKVROW * II * 2;
  __hip_bfloat16* Vt2 = (__hip_bfloat16*)ws;  ws += (size_t)NKVROW * II * 2;
  __hip_bfloat16* Op  = (__hip_bfloat16*)ws;  ws += (size_t)NSPLIT * NROW * II * 2;
  float* Mp           = (float*)ws;           ws += (size_t)NSPLIT * 24 * 2 * TT * 4;
  float* Lp           = (float*)ws;           ws += (size_t)NSPLIT * 24 * 2 * TT * 4;
  __hip_bfloat16* Bkv = (__hip_bfloat16*)ws;  ws += (size_t)128 * 768 * 2;
  __hip_bfloat16* Bq  = (__hip_bfloat16*)ws;  ws += (size_t)NDOM * 64 * 768 * 2;
  __hip_bfloat16* Bo  = (__hip_bfloat16*)ws;  ws += (size_t)NDOM * 768 * 64 * 2;
  float* bias2        = (float*)ws;           ws += (size_t)BB * SS * 4;

  const int PREP_N = 128*768 + NDOM*64*768 + NDOM*768*64 + BB*SS;
  prep_kernel<<<(PREP_N + 255) / 256, 256, 0, stream>>>(mask, Wk, Wv, Wq, Wo, Bkv, Bq, Bo, bias2);
  qkv_gemm_kernel<<<NKVB + NQB, 256, 0, stream>>>(x, hist, Bkv, Bq, Qb, Kh, Vt2);
  attn_kernel<<<48 * 8 * NSPLIT, 256, 0, stream>>>(Qb, Kh, Vt2, bias2, Op, Mp, Lp);
  oproj_ln_kernel<<<NROW / 32, 256, 0, stream>>>(x, Op, Mp, Lp, Bo, gamma, beta, out);
}

// Round 16
// 204.704 us; speedup vs baseline: 1.0270x; 1.0270x over previous
//
#include <hip/hip_runtime.h>
#include <hip/hip_bf16.h>
#include <math.h>

#define NDOM 6
#define BB 4
#define TT 1024
#define DD 768
#define PP 3
#define HH 2
#define DHH 32
#define II 64
#define SS (PP*TT)        // 3072
#define NROW (NDOM*BB*TT) // 24576
#define NKVROW (NDOM*BB*SS)
#define NSPLIT 4
#define NITER (SS/NSPLIT/64)   // 12
#define NKVB (NKVROW/128) // 576
#define NQB  (NROW/128)   // 192
#define LNEPS 1e-5f

typedef unsigned int uint;
typedef uint  u32x4  __attribute__((ext_vector_type(4)));
typedef int   i32x2  __attribute__((ext_vector_type(2)));
typedef float f32x2  __attribute__((ext_vector_type(2)));
typedef float f32x4  __attribute__((ext_vector_type(4)));
typedef float f32x16 __attribute__((ext_vector_type(16)));
typedef __bf16 bf16x8 __attribute__((ext_vector_type(8)));

// D = A(32x16) * B(16x32) + C.  A row = lane&31, k = (lane>>5)*8+j.
// B col = lane&31, k = (lane>>5)*8+j.  D: col = lane&31, row=(r&3)+8*(r>>2)+4*(lane>>5).
__device__ __forceinline__ f32x16 mfma32(u32x4 a, u32x4 b, f32x16 c) {
  return __builtin_amdgcn_mfma_f32_32x32x16_bf16(
      __builtin_bit_cast(bf16x8, a), __builtin_bit_cast(bf16x8, b), c, 0, 0, 0);
}

__device__ __forceinline__ uint pkbf(float a, float b) {
  union { __bf16 h[2]; uint u; } v;
  v.h[0] = (__bf16)a; v.h[1] = (__bf16)b;
  return v.u;
}
__device__ __forceinline__ float b2f(uint u16) {
  union { uint i; float f; } v; v.i = u16 << 16; return v.f;
}

// x gets {a_lo | partner's b}, y gets {partner's a | b}  (32-lane halves)
__device__ __forceinline__ void plswap(uint a, uint b, uint& x, uint& y) {
#if __has_builtin(__builtin_amdgcn_permlane32_swap)
  i32x2 r = __builtin_amdgcn_permlane32_swap((int)a, (int)b, false, false);
  x = (uint)r.x; y = (uint)r.y;
#else
  uint sa = __shfl_xor(a, 32), sb = __shfl_xor(b, 32);
  bool h1 = (threadIdx.x & 32) != 0;
  x = h1 ? sb : a;
  y = h1 ? b : sa;
#endif
}

// async global->LDS, 16B per lane.  LDS dest = wave-uniform base + lane*16.
#if __has_builtin(__builtin_amdgcn_global_load_lds)
#define HAS_GLL 1
typedef __attribute__((address_space(3))) uint lds_u32;
typedef __attribute__((address_space(1))) uint glb_u32;
__device__ __forceinline__ void gll16(const void* src, void* lds_base) {
  __builtin_amdgcn_global_load_lds((const glb_u32*)src, (lds_u32*)lds_base, 16, 0, 0);
}
#else
#define HAS_GLL 0
#endif

// ---------------------------------------------------------------------------
// Prep: bf16 transposed weights.  B-side pre-XOR-swizzled within each 32-k
// half-chunk (4 slots of 8 bf16): element (c, kk32*32 + (u^(c&3))*8 + e) is
// stored at (c, kk32*32 + u*8 + e), so a LINEAR global_load_lds yields
// LDS[c][u] = B[c][u ^ (c&3)].  Bo row-major; exp2-domain mask bias.
// ---------------------------------------------------------------------------
__global__ __launch_bounds__(256) void prep_kernel(
    const int* __restrict__ mask, const float* __restrict__ Wk,
    const float* __restrict__ Wv, const float* __restrict__ Wq,
    const float* __restrict__ Wo,
    __hip_bfloat16* __restrict__ Bkv, __hip_bfloat16* __restrict__ Bq,
    __hip_bfloat16* __restrict__ Bo, float* __restrict__ bias2)
{
  int i = blockIdx.x * 256 + threadIdx.x;
  const int N1 = 128 * 768;          // Bkv (swizzled)
  const int N2 = NDOM * 64 * 768;    // Bq  (swizzled)
  const int N3 = NDOM * 768 * 64;    // Bo
  if (i < N1) {
    int c = i / 768, kd = i % 768;
    int e = kd & 7, ud = (kd >> 3) & 3, kk = kd >> 5;
    int k = (kk << 5) + ((ud ^ (c & 3)) << 3) + e;
    float v = (c < 64) ? Wk[k * 64 + c] : Wv[k * 64 + (c - 64)];
    Bkv[i] = __float2bfloat16(v);
  } else if (i < N1 + N2) {
    int j = i - N1;
    int n = j / (64 * 768);
    int rem = j % (64 * 768);
    int c = rem / 768, kd = rem % 768;
    int e = kd & 7, ud = (kd >> 3) & 3, kk = kd >> 5;
    int k = (kk << 5) + ((ud ^ (c & 3)) << 3) + e;
    Bq[j] = __float2bfloat16(Wq[((size_t)n * 768 + k) * 64 + c]);
  } else if (i < N1 + N2 + N3) {
    int j = i - N1 - N2;
    int n = j / (768 * 64);
    int rem = j % (768 * 64);
    int d = rem / 64, k = rem % 64;
    Bo[j] = __float2bfloat16(Wo[((size_t)n * 64 + k) * 768 + d]);
  } else if (i < N1 + N2 + N3 + BB * SS) {
    int j = i - N1 - N2 - N3;
    int b = j / SS, s = j % SS;
    bias2[j] = (1.0f - (float)mask[b * TT + (s & (TT - 1))]) * (-14426.950408889634f);
  }
}

// ---------------------------------------------------------------------------
// Fused Q + KV projection GEMM: BM=128, 32-k half-chunks, DOUBLE-BUFFERED
// with counted vmcnt (T3+T4): stage(h+1) issues BEFORE the wait; vmcnt(N)
// retires exactly half h's glls, leaving h+1's in flight across both raw
// s_barriers.  LDS stays 48 KB (2 x (16KB A-f32 + 8KB B-bf16)) = 3 blocks/CU.
// Compute is vmem-free (ds_read + cvt_pk + MFMA).  Store paths unchanged.
// Blocks [0,576): history -> Kh + Vt2.  [576,768): x -> Q.
// ---------------------------------------------------------------------------
__global__ __launch_bounds__(256) void qkv_gemm_kernel(
    const float* __restrict__ x, const float* __restrict__ hist,
    const __hip_bfloat16* __restrict__ Bkv, const __hip_bfloat16* __restrict__ Bq,
    __hip_bfloat16* __restrict__ Qo, __hip_bfloat16* __restrict__ Kh,
    __hip_bfloat16* __restrict__ Vt2)
{
  __shared__ float As[2][128 * 32];           // 2 x 16 KB
  __shared__ __hip_bfloat16 Bs[2][128 * 32];  // 2 x 8 KB
  const int tid = threadIdx.x;
  const int lane = tid & 63, w = tid >> 6;
  const int cl = lane & 31, hi = lane >> 5;

  const bool isKV = blockIdx.x < NKVB;
  const float* Asrc;
  int nb = 0, s0 = 0, n = 0, brow = 0;
  if (isKV) {
    brow = blockIdx.x * 128;
    nb = brow / SS; n = nb >> 2;
    int b = nb & 3;
    s0 = brow % SS;
    int p = s0 / TT, t0 = s0 % TT;          // 128 | 1024: block stays in one p
    Asrc = hist + (((size_t)(p * NDOM + n) * BB + b) * TT + t0) * 768;
  } else {
    brow = (blockIdx.x - NKVB) * 128;
    n = brow >> 12;
    Asrc = x + (size_t)brow * 768;
  }
  const __hip_bfloat16* Bsrc = isKV ? Bkv : (Bq + (size_t)n * 64 * 768);

  const int lrowA = lane >> 3, lslotA = lane & 7;   // A: 8 rows x 8 slots/gll
  const int lrowB = lane >> 2, lslotB = lane & 3;   // B: 16 rows x 4 slots/gll

  // stage A half h (k = h*32..+32): wave w rows [w*32, +32), 4 glls.
  // LDS[row][s] = G[row][s ^ (row&7)]  (16B slots, swizzle on SOURCE).
  auto stageA = [&](int h, int buf) {
#pragma unroll
    for (int j = 0; j < 4; ++j) {
      int row0 = w * 32 + j * 8;
      int row = row0 + lrowA;
      int gs = lslotA ^ (row & 7);
      const float* src = Asrc + (size_t)row * 768 + h * 32 + gs * 4;
#if HAS_GLL
      gll16(src, &As[buf][row0 * 32]);
#else
      *(f32x4*)(&As[buf][row0 * 32] + lane * 4) = *(const f32x4*)src;
#endif
    }
  };
  // stage B half h: KV 128 cols (2 glls/wave), Q 64 cols (1 gll/wave).
  auto stageB = [&](int h, int buf, int nglB) {
#pragma unroll
    for (int j = 0; j < 2; ++j) {
      if (j < nglB) {
        int c0 = w * 16 * nglB + j * 16;
        int c = c0 + lrowB;
        const __hip_bfloat16* src = Bsrc + (size_t)c * 768 + h * 32 + lslotB * 8;
#if HAS_GLL
        gll16(src, &Bs[buf][c0 * 32]);
#else
        *(u32x4*)(&Bs[buf][c0 * 32] + lane * 8) = *(const u32x4*)src;
#endif
      }
    }
  };

  f32x16 acc[4] = {};
  const int rowR = w * 32 + cl;

  auto computeHalf = [&](int buf, int NACC) {
#pragma unroll
    for (int ks = 0; ks < 2; ++ks) {
      int t = ks * 4 + hi * 2;
      f32x4 a0 = *(const f32x4*)&As[buf][rowR * 32 + ((t       ^ (rowR & 7)) * 4)];
      f32x4 a1 = *(const f32x4*)&As[buf][rowR * 32 + (((t + 1) ^ (rowR & 7)) * 4)];
      u32x4 a = {pkbf(a0.x, a0.y), pkbf(a0.z, a0.w), pkbf(a1.x, a1.y), pkbf(a1.z, a1.w)};
      int u0 = ks * 2 + hi;
#pragma unroll
      for (int g = 0; g < 4; ++g) {
        if (g < NACC) {
          int c = g * 32 + cl;
          u32x4 b = *(const u32x4*)&Bs[buf][c * 32 + ((u0 ^ (c & 3)) * 8)];
          acc[g] = mfma32(a, b, acc[g]);
        }
      }
    }
  };

  if (isKV) {
    stageA(0, 0); stageB(0, 0, 2);            // 6 glls in flight
#pragma unroll 2
    for (int h = 0; h < 24; ++h) {
      if (h + 1 < 24) {
        stageA(h + 1, (h + 1) & 1); stageB(h + 1, (h + 1) & 1, 2);
        asm volatile("s_waitcnt vmcnt(6)" ::: "memory");
      } else {
        asm volatile("s_waitcnt vmcnt(0)" ::: "memory");
      }
      __builtin_amdgcn_s_barrier();
      computeHalf(h & 1, 4);
      __builtin_amdgcn_s_barrier();
    }
    // K store: acc0/acc1 = K heads 0/1 (head-split rows of 64B)
    {
      const size_t base0 = (size_t)(nb * 2 + 0) * SS;
      const size_t base1 = (size_t)(nb * 2 + 1) * SS;
#pragma unroll
      for (int r = 0; r < 16; ++r) {
        int rl = (r & 3) + 8 * (r >> 2) + 4 * hi;
        int s  = s0 + w * 32 + rl;
        Kh[(base0 + s) * 32 + cl] = __float2bfloat16(acc[0][r]);
        Kh[(base1 + s) * 32 + cl] = __float2bfloat16(acc[1][r]);
      }
    }
    // V store: acc2/acc3 = V heads 0/1 -> Vt2[nb][h][sb][c][8]
#pragma unroll
    for (int k = 0; k < 4; ++k) {
      int sb = (s0 + w * 32 + 8 * k) >> 3;
      size_t A0 = (((size_t)(nb * 2 + 0) * (SS / 8) + sb) * 32 + cl) * 8 + 4 * hi;
      size_t A1 = (((size_t)(nb * 2 + 1) * (SS / 8) + sb) * 32 + cl) * 8 + 4 * hi;
      *(uint2*)(Vt2 + A0) = uint2{pkbf(acc[2][4*k], acc[2][4*k+1]), pkbf(acc[2][4*k+2], acc[2][4*k+3])};
      *(uint2*)(Vt2 + A1) = uint2{pkbf(acc[3][4*k], acc[3][4*k+1]), pkbf(acc[3][4*k+2], acc[3][4*k+3])};
    }
  } else {
    stageA(0, 0); stageB(0, 0, 1);            // 5 glls in flight
#pragma unroll 2
    for (int h = 0; h < 24; ++h) {
      if (h + 1 < 24) {
        stageA(h + 1, (h + 1) & 1); stageB(h + 1, (h + 1) & 1, 1);
        asm volatile("s_waitcnt vmcnt(5)" ::: "memory");
      } else {
        asm volatile("s_waitcnt vmcnt(0)" ::: "memory");
      }
      __builtin_amdgcn_s_barrier();
      computeHalf(h & 1, 2);
      __builtin_amdgcn_s_barrier();
    }
#pragma unroll
    for (int r = 0; r < 16; ++r) {
      int rl = (r & 3) + 8 * (r >> 2) + 4 * hi;
      size_t rb = (size_t)(brow + w * 32 + rl) * 64;
      Qo[rb + cl]      = __float2bfloat16(acc[0][r]);
      Qo[rb + 32 + cl] = __float2bfloat16(acc[1][r]);
    }
  }
}

// ---------------------------------------------------------------------------
// Flash attention, split-S by 4 (round-14 proven config).  Block = 4 waves
// sharing one (n,b,h,split); lockstep K/V streams (L1 broadcast), no LDS.
// ---------------------------------------------------------------------------
struct KV { u32x4 k0, k1, k2, k3, v0, v1, v2, v3; };

__global__ __launch_bounds__(256) void attn_kernel(
    const __hip_bfloat16* __restrict__ Q, const __hip_bfloat16* __restrict__ Kh,
    const __hip_bfloat16* __restrict__ Vt2, const float* __restrict__ bias2,
    __hip_bfloat16* __restrict__ Op, float* __restrict__ Mp, float* __restrict__ Lp)
{
  const int tid = threadIdx.x;
  const int lane = tid & 63, w = tid >> 6;
  const int cl = lane & 31, hi = lane >> 5;
  const int bid = blockIdx.x;
  const int g = bid % 48;            // (n,b,h) group -> fixed XCD (48 % 8 == 0)
  const int rest = bid / 48;         // 0..31
  const int sp = rest >> 3;          // split 0..3
  const int tq = rest & 7;           // q super-tile 0..7
  const int qtile = tq * 4 + w;      // 0..31
  const int h = g & 1, nb = g >> 1;
  const int b = nb & 3;
  const int qrow = nb * TT + qtile * 32;
  const int sbase = sp * (SS / NSPLIT);   // 768 keys per split

  const __hip_bfloat16* Qp = Q + (size_t)(qrow + cl) * 64 + h * 32 + hi * 8;
  u32x4 qf0 = *(const u32x4*)Qp;
  u32x4 qf1 = *(const u32x4*)(Qp + 16);

  const __hip_bfloat16* Kp = Kh + ((size_t)(nb * 2 + h) * SS + sbase) * 32;
  const __hip_bfloat16* Vp = Vt2 + (size_t)(nb * 2 + h) * SS * 32 + (size_t)sbase * 32;
  const float* Bp = bias2 + b * SS + sbase + hi * 4;

  const float scale2 = 0.17677669529663687f * 1.4426950408889634f;
  const f32x2 sc2 = {scale2, scale2};

  f32x16 ot = {};
  float m = -1e30f, lsum = 0.f;

  auto loadKV = [&](int it) {
    KV t;
    const __hip_bfloat16* kp = Kp + (size_t)it * 64 * 32;
    t.k0 = *(const u32x4*)(kp + cl * 32 + hi * 8);
    t.k1 = *(const u32x4*)(kp + cl * 32 + 16 + hi * 8);
    t.k2 = *(const u32x4*)(kp + 1024 + cl * 32 + hi * 8);
    t.k3 = *(const u32x4*)(kp + 1024 + cl * 32 + 16 + hi * 8);
    const __hip_bfloat16* vp = Vp + (size_t)it * 64 * 32;
    t.v0 = *(const u32x4*)(vp + ((0 * 2 + hi) * 32 + cl) * 8);
    t.v1 = *(const u32x4*)(vp + ((1 * 2 + hi) * 32 + cl) * 8);
    t.v2 = *(const u32x4*)(vp + ((2 * 2 + hi) * 32 + cl) * 8);
    t.v3 = *(const u32x4*)(vp + ((3 * 2 + hi) * 32 + cl) * 8);
    return t;
  };

  auto compute = [&](const KV& t, int it) {
    f32x16 pz0 = {}, pz1 = {};
    pz0 = mfma32(t.k0, qf0, pz0);
    pz0 = mfma32(t.k1, qf1, pz0);
    pz1 = mfma32(t.k2, qf0, pz1);
    pz1 = mfma32(t.k3, qf1, pz1);
    const float* bp = Bp + it * 64;
    f32x4 b4[8];
#pragma unroll
    for (int q = 0; q < 8; ++q) b4[q] = *(const f32x4*)(bp + 8 * q);
    f32x2 p2[16];
#pragma unroll
    for (int i = 0; i < 8; ++i) {
      f32x4 bq0 = b4[i >> 1];
      f32x4 bq1 = b4[4 + (i >> 1)];
      f32x2 bv0 = (i & 1) ? f32x2{bq0.z, bq0.w} : f32x2{bq0.x, bq0.y};
      f32x2 bv1 = (i & 1) ? f32x2{bq1.z, bq1.w} : f32x2{bq1.x, bq1.y};
      p2[i]     = f32x2{pz0[2*i], pz0[2*i+1]} * sc2 + bv0;
      p2[8 + i] = f32x2{pz1[2*i], pz1[2*i+1]} * sc2 + bv1;
    }
    f32x2 mx = p2[0];
#pragma unroll
    for (int i = 1; i < 16; ++i) {
      mx.x = fmaxf(mx.x, p2[i].x);
      mx.y = fmaxf(mx.y, p2[i].y);
    }
    float tm = fmaxf(mx.x, mx.y);
    tm = fmaxf(tm, __shfl_xor(tm, 32));
    if (!__all(tm - m <= 8.f)) {       // defer-max
      float mn = fmaxf(m, tm);
      float f = exp2f(m - mn);
#pragma unroll
      for (int i = 0; i < 16; ++i) ot[i] *= f;
      lsum *= f;
      m = mn;
    }
    const f32x2 m2 = {m, m};
    f32x2 s2 = {0.f, 0.f};
#pragma unroll
    for (int i = 0; i < 16; ++i) {
      f32x2 d = p2[i] - m2;
      f32x2 e = {exp2f(d.x), exp2f(d.y)};
      p2[i] = e;
      s2 += e;
    }
    float ts = s2.x + s2.y;
    ts += __shfl_xor(ts, 32);
    lsum += ts;
    // P -> bf16 B-frags via permlane32_swap
    uint cv[16];
#pragma unroll
    for (int i = 0; i < 16; ++i) cv[i] = pkbf(p2[i].x, p2[i].y);
    u32x4 pf0, pf1, pf2, pf3;
    {
      uint x0, y0, x1, y1;
      plswap(cv[0], cv[2],  x0, y0); plswap(cv[1], cv[3],  x1, y1);
      pf0 = u32x4{x0, x1, y0, y1};
      plswap(cv[4], cv[6],  x0, y0); plswap(cv[5], cv[7],  x1, y1);
      pf1 = u32x4{x0, x1, y0, y1};
      plswap(cv[8], cv[10], x0, y0); plswap(cv[9], cv[11], x1, y1);
      pf2 = u32x4{x0, x1, y0, y1};
      plswap(cv[12], cv[14], x0, y0); plswap(cv[13], cv[15], x1, y1);
      pf3 = u32x4{x0, x1, y0, y1};
    }
    ot = mfma32(t.v0, pf0, ot);
    ot = mfma32(t.v1, pf1, ot);
    ot = mfma32(t.v2, pf2, ot);
    ot = mfma32(t.v3, pf3, ot);
  };

  KV cur = loadKV(0);
#pragma unroll 1
  for (int it = 0; it < NITER; ++it) {
    KV nxt = loadKV(it + 1 < NITER ? it + 1 : NITER - 1);
    compute(cur, it);
    cur = nxt;
    __builtin_amdgcn_s_barrier();   // keep the 4 waves' K/V streams in lockstep (L1 reuse)
  }

  // store unnormalized O^T partial (bf16) + m/l
  __hip_bfloat16* op = Op + ((size_t)sp * NROW + qrow + cl) * 64 + h * 32 + 4 * hi;
#pragma unroll
  for (int k = 0; k < 4; ++k) {
    uint2 wv = {pkbf(ot[4*k], ot[4*k+1]), pkbf(ot[4*k+2], ot[4*k+3])};
    *(uint2*)(op + 8 * k) = wv;
  }
  if (lane < 32) {
    int mi = ((sp * 24 + nb) * 2 + h) * TT + qtile * 32 + cl;
    Mp[mi] = m;
    Lp[mi] = lsum;
  }
}

// ---------------------------------------------------------------------------
// Fused split-combine + out-projection (MFMA) + residual + LayerNorm.
// Block 256 = 4 waves, 32 rows; wave w owns cols [w*192, +192).
// ---------------------------------------------------------------------------
__global__ __launch_bounds__(256) void oproj_ln_kernel(
    const float* __restrict__ x, const __hip_bfloat16* __restrict__ Op,
    const float* __restrict__ Mp, const float* __restrict__ Lp,
    const __hip_bfloat16* __restrict__ Bo, const float* __restrict__ gamma,
    const float* __restrict__ beta, float* __restrict__ out)
{
  __shared__ float red[4][32][2];
  __shared__ float redf[32][2];
  const int tid = threadIdx.x;
  const int lane = tid & 63, w = tid >> 6;
  const int cl = lane & 31, hi = lane >> 5;
  const int row0 = blockIdx.x * 32;
  const int n = row0 >> 12;
  const int nb = row0 >> 10;
  const int trow = (row0 & 1023) + cl;
  const int MLS = 24 * 2 * TT;

  // combine weights per head
  float wsp[2][NSPLIT];
#pragma unroll
  for (int h = 0; h < 2; ++h) {
    int mi = (nb * 2 + h) * TT + trow;
    float mv[NSPLIT], lv[NSPLIT];
#pragma unroll
    for (int sp = 0; sp < NSPLIT; ++sp) { mv[sp] = Mp[mi + sp * MLS]; lv[sp] = Lp[mi + sp * MLS]; }
    float ms = mv[0];
#pragma unroll
    for (int sp = 1; sp < NSPLIT; ++sp) ms = fmaxf(ms, mv[sp]);
    float den = 0.f;
#pragma unroll
    for (int sp = 0; sp < NSPLIT; ++sp) { wsp[h][sp] = exp2f(mv[sp] - ms); den = fmaf(lv[sp], wsp[h][sp], den); }
    float inv = 1.0f / den;
#pragma unroll
    for (int sp = 0; sp < NSPLIT; ++sp) wsp[h][sp] *= inv;
  }

  // A-frags: combine partials
  u32x4 af[4];
#pragma unroll
  for (int ks = 0; ks < 4; ++ks) {
    int h = ks >> 1;
    size_t off = (size_t)(row0 + cl) * 64 + ks * 16 + hi * 8;
    f32x2 s0 = {}, s1 = {}, s2 = {}, s3 = {};
#pragma unroll
    for (int sp = 0; sp < NSPLIT; ++sp) {
      u32x4 v = *(const u32x4*)(Op + (size_t)sp * NROW * 64 + off);
      float wv = wsp[h][sp];
      s0 += f32x2{b2f(v[0] & 0xffffu), b2f(v[0] >> 16)} * wv;
      s1 += f32x2{b2f(v[1] & 0xffffu), b2f(v[1] >> 16)} * wv;
      s2 += f32x2{b2f(v[2] & 0xffffu), b2f(v[2] >> 16)} * wv;
      s3 += f32x2{b2f(v[3] & 0xffffu), b2f(v[3] >> 16)} * wv;
    }
    af[ks] = u32x4{pkbf(s0.x, s0.y), pkbf(s1.x, s1.y), pkbf(s2.x, s2.y), pkbf(s3.x, s3.y)};
  }

  const __hip_bfloat16* Bp = Bo + ((size_t)n * 768 + w * 192 + cl) * 64 + hi * 8;
  f32x16 acc[6] = {};
#pragma unroll
  for (int ks = 0; ks < 4; ++ks) {
#pragma unroll
    for (int t = 0; t < 6; ++t) {
      u32x4 bb = *(const u32x4*)(Bp + (size_t)(t * 32) * 64 + ks * 16);
      acc[t] = mfma32(af[ks], bb, acc[t]);
    }
  }

  float s1[16], s2[16];
#pragma unroll
  for (int r = 0; r < 16; ++r) { s1[r] = 0.f; s2[r] = 0.f; }
#pragma unroll
  for (int t = 0; t < 6; ++t) {
#pragma unroll
    for (int r = 0; r < 16; ++r) {
      int R = (r & 3) + 8 * (r >> 2) + 4 * hi;
      int col = w * 192 + t * 32 + cl;
      float y = acc[t][r] + x[(size_t)(row0 + R) * 768 + col];
      acc[t][r] = y;
      s1[r] += y;
      s2[r] = fmaf(y, y, s2[r]);
    }
  }
#pragma unroll
  for (int r = 0; r < 16; ++r) {
#pragma unroll
    for (int off = 1; off < 32; off <<= 1) {
      s1[r] += __shfl_xor(s1[r], off);
      s2[r] += __shfl_xor(s2[r], off);
    }
  }
  if (cl == 0) {
#pragma unroll
    for (int r = 0; r < 16; ++r) {
      int R = (r & 3) + 8 * (r >> 2) + 4 * hi;
      red[w][R][0] = s1[r];
      red[w][R][1] = s2[r];
    }
  }
  __syncthreads();
  if (tid < 64) {
    int R = tid & 31, st = tid >> 5;
    redf[R][st] = red[0][R][st] + red[1][R][st] + red[2][R][st] + red[3][R][st];
  }
  __syncthreads();

  float gv[6], bv[6];
#pragma unroll
  for (int t = 0; t < 6; ++t) {
    int col = w * 192 + t * 32 + cl;
    gv[t] = gamma[n * 768 + col];
    bv[t] = beta[n * 768 + col];
  }
#pragma unroll
  for (int r = 0; r < 16; ++r) {
    int R = (r & 3) + 8 * (r >> 2) + 4 * hi;
    float mu = redf[R][0] * (1.0f / 768.0f);
    float var = redf[R][1] * (1.0f / 768.0f) - mu * mu;
    float rs = rsqrtf(var + LNEPS);
#pragma unroll
    for (int t = 0; t < 6; ++t) {
      int col = w * 192 + t * 32 + cl;
      out[(size_t)(row0 + R) * 768 + col] = (acc[t][r] - mu) * rs * gv[t] + bv[t];
    }
  }
}

// ---------------------------------------------------------------------------
extern "C" void kernel_launch(void* const* d_in, const int* in_sizes, int n_in,
                              void* d_out, int out_size, void* d_ws, size_t ws_size,
                              hipStream_t stream) {
  const float* x     = (const float*)d_in[0];
  const float* hist  = (const float*)d_in[1];
  const int*   mask  = (const int*)d_in[2];
  const float* Wq    = (const float*)d_in[3];
  const float* Wk    = (const float*)d_in[4];
  const float* Wv    = (const float*)d_in[5];
  const float* Wo    = (const float*)d_in[6];
  const float* gamma = (const float*)d_in[7];
  const float* beta  = (const float*)d_in[8];
  float* out = (float*)d_out;

  char* ws = (char*)d_ws;
  __hip_bfloat16* Qb  = (__hip_bfloat16*)ws;  ws += (size_t)NROW * II * 2;
  __hip_bfloat16* Kh  = (__hip_bfloat16*)ws;  ws += (size_t)NKVROW * II * 2;
  __hip_bfloat16* Vt2 = (__hip_bfloat16*)ws;  ws += (size_t)NKVROW * II * 2;
  __hip_bfloat16* Op  = (__hip_bfloat16*)ws;  ws += (size_t)NSPLIT * NROW * II * 2;
  float* Mp           = (float*)ws;           ws += (size_t)NSPLIT * 24 * 2 * TT * 4;
  float* Lp           = (float*)ws;           ws += (size_t)NSPLIT * 24 * 2 * TT * 4;
  __hip_bfloat16* Bkv = (__hip_bfloat16*)ws;  ws += (size_t)128 * 768 * 2;
  __hip_bfloat16* Bq  = (__hip_bfloat16*)ws;  ws += (size_t)NDOM * 64 * 768 * 2;
  __hip_bfloat16* Bo  = (__hip_bfloat16*)ws;  ws += (size_t)NDOM * 768 * 64 * 2;
  float* bias2        = (float*)ws;           ws += (size_t)BB * SS * 4;

  const int PREP_N = 128*768 + NDOM*64*768 + NDOM*768*64 + BB*SS;
  prep_kernel<<<(PREP_N + 255) / 256, 256, 0, stream>>>(mask, Wk, Wv, Wq, Wo, Bkv, Bq, Bo, bias2);
  qkv_gemm_kernel<<<NKVB + NQB, 256, 0, stream>>>(x, hist, Bkv, Bq, Qb, Kh, Vt2);
  attn_kernel<<<48 * 8 * NSPLIT, 256, 0, stream>>>(Qb, Kh, Vt2, bias2, Op, Mp, Lp);
  oproj_ln_kernel<<<NROW / 32, 256, 0, stream>>>(x, Op, Mp, Lp, Bo, gamma, beta, out);
}

// Round 17
// 200.852 us; speedup vs baseline: 1.0467x; 1.0192x over previous
//
#include <hip/hip_runtime.h>
#include <hip/hip_bf16.h>
#include <math.h>

#define NDOM 6
#define BB 4
#define TT 1024
#define DD 768
#define PP 3
#define HH 2
#define DHH 32
#define II 64
#define SS (PP*TT)        // 3072
#define NROW (NDOM*BB*TT) // 24576
#define NKVROW (NDOM*BB*SS)
#define NSPLIT 4
#define NITER (SS/NSPLIT/64)   // 12
#define NKVB (NKVROW/128) // 576
#define NQB  (NROW/128)   // 192
#define LNEPS 1e-5f

typedef unsigned int uint;
typedef uint  u32x4  __attribute__((ext_vector_type(4)));
typedef int   i32x2  __attribute__((ext_vector_type(2)));
typedef float f32x2  __attribute__((ext_vector_type(2)));
typedef float f32x4  __attribute__((ext_vector_type(4)));
typedef float f32x16 __attribute__((ext_vector_type(16)));
typedef __bf16 bf16x8 __attribute__((ext_vector_type(8)));

// D = A(32x16) * B(16x32) + C.  A row = lane&31, k = (lane>>5)*8+j.
// B col = lane&31, k = (lane>>5)*8+j.  D: col = lane&31, row=(r&3)+8*(r>>2)+4*(lane>>5).
__device__ __forceinline__ f32x16 mfma32(u32x4 a, u32x4 b, f32x16 c) {
  return __builtin_amdgcn_mfma_f32_32x32x16_bf16(
      __builtin_bit_cast(bf16x8, a), __builtin_bit_cast(bf16x8, b), c, 0, 0, 0);
}

__device__ __forceinline__ uint pkbf(float a, float b) {
  union { __bf16 h[2]; uint u; } v;
  v.h[0] = (__bf16)a; v.h[1] = (__bf16)b;
  return v.u;
}
__device__ __forceinline__ float b2f(uint u16) {
  union { uint i; float f; } v; v.i = u16 << 16; return v.f;
}

// x gets {a_lo | partner's b}, y gets {partner's a | b}  (32-lane halves)
__device__ __forceinline__ void plswap(uint a, uint b, uint& x, uint& y) {
#if __has_builtin(__builtin_amdgcn_permlane32_swap)
  i32x2 r = __builtin_amdgcn_permlane32_swap((int)a, (int)b, false, false);
  x = (uint)r.x; y = (uint)r.y;
#else
  uint sa = __shfl_xor(a, 32), sb = __shfl_xor(b, 32);
  bool h1 = (threadIdx.x & 32) != 0;
  x = h1 ? sb : a;
  y = h1 ? b : sa;
#endif
}

// async global->LDS, 16B per lane.  LDS dest = wave-uniform base + lane*16.
#if __has_builtin(__builtin_amdgcn_global_load_lds)
#define HAS_GLL 1
typedef __attribute__((address_space(3))) uint lds_u32;
typedef __attribute__((address_space(1))) uint glb_u32;
__device__ __forceinline__ void gll16(const void* src, void* lds_base) {
  __builtin_amdgcn_global_load_lds((const glb_u32*)src, (lds_u32*)lds_base, 16, 0, 0);
}
#else
#define HAS_GLL 0
#endif

// ---------------------------------------------------------------------------
// Prep: bf16 transposed weights (B-side pre-XOR-swizzled within each 64-k
// chunk so a LINEAR global_load_lds yields LDS[c][u] = B[c][u^(c&7)]),
// Bo row-major, exp2-domain mask bias.   (round-14 proven layout)
// ---------------------------------------------------------------------------
__global__ __launch_bounds__(256) void prep_kernel(
    const int* __restrict__ mask, const float* __restrict__ Wk,
    const float* __restrict__ Wv, const float* __restrict__ Wq,
    const float* __restrict__ Wo,
    __hip_bfloat16* __restrict__ Bkv, __hip_bfloat16* __restrict__ Bq,
    __hip_bfloat16* __restrict__ Bo, float* __restrict__ bias2)
{
  int i = blockIdx.x * 256 + threadIdx.x;
  const int N1 = 128 * 768;          // Bkv (swizzled)
  const int N2 = NDOM * 64 * 768;    // Bq  (swizzled)
  const int N3 = NDOM * 768 * 64;    // Bo
  if (i < N1) {
    int c = i / 768, kd = i % 768;
    int e = kd & 7, ud = (kd >> 3) & 7, kk = kd >> 6;
    int k = (kk << 6) + ((ud ^ (c & 7)) << 3) + e;
    float v = (c < 64) ? Wk[k * 64 + c] : Wv[k * 64 + (c - 64)];
    Bkv[i] = __float2bfloat16(v);
  } else if (i < N1 + N2) {
    int j = i - N1;
    int n = j / (64 * 768);
    int rem = j % (64 * 768);
    int c = rem / 768, kd = rem % 768;
    int e = kd & 7, ud = (kd >> 3) & 7, kk = kd >> 6;
    int k = (kk << 6) + ((ud ^ (c & 7)) << 3) + e;
    Bq[j] = __float2bfloat16(Wq[((size_t)n * 768 + k) * 64 + c]);
  } else if (i < N1 + N2 + N3) {
    int j = i - N1 - N2;
    int n = j / (768 * 64);
    int rem = j % (768 * 64);
    int d = rem / 64, k = rem % 64;
    Bo[j] = __float2bfloat16(Wo[((size_t)n * 64 + k) * 768 + d]);
  } else if (i < N1 + N2 + N3 + BB * SS) {
    int j = i - N1 - N2 - N3;
    int b = j / SS, s = j % SS;
    bias2[j] = (1.0f - (float)mask[b * TT + (s & (TT - 1))]) * (-14426.950408889634f);
  }
}

// ---------------------------------------------------------------------------
// Fused Q + KV projection GEMM, m97 structure (round-14 PROVEN OPTIMUM of 8
// variants — do not restructure): BM=128, BK=64, BOTH operands staged per
// chunk via global_load_lds (contiguous 1KB/instr), single LDS buffer,
// sync -> vmem-free compute (ds_read + cvt_pk + MFMA) -> sync.
// A: f32 LDS, 16-slot(256B-row) XOR swizzle on the per-lane GLOBAL source.
// B: bf16 LDS, 8-slot swizzle pre-applied in prep's global layout.
// NOTE (round-16 lesson): halving chunk granularity shrinks LDS row stride
// and reintroduces 4-way bank conflicts — the swizzle geometry is load-bearing.
// ---------------------------------------------------------------------------
__global__ __launch_bounds__(256) void qkv_gemm_kernel(
    const float* __restrict__ x, const float* __restrict__ hist,
    const __hip_bfloat16* __restrict__ Bkv, const __hip_bfloat16* __restrict__ Bq,
    __hip_bfloat16* __restrict__ Qo, __hip_bfloat16* __restrict__ Kh,
    __hip_bfloat16* __restrict__ Vt2)
{
  __shared__ float As[128 * 64];            // 32 KB
  __shared__ __hip_bfloat16 Bs[128 * 64];   // 16 KB
  const int tid = threadIdx.x;
  const int lane = tid & 63, w = tid >> 6;
  const int cl = lane & 31, hi = lane >> 5;

  const bool isKV = blockIdx.x < NKVB;
  const float* Asrc;
  int nb = 0, s0 = 0, n = 0, brow = 0;
  if (isKV) {
    brow = blockIdx.x * 128;
    nb = brow / SS; n = nb >> 2;
    int b = nb & 3;
    s0 = brow % SS;
    int p = s0 / TT, t0 = s0 % TT;          // 128 | 1024: block stays in one p
    Asrc = hist + (((size_t)(p * NDOM + n) * BB + b) * TT + t0) * 768;
  } else {
    brow = (blockIdx.x - NKVB) * 128;
    n = brow >> 12;
    Asrc = x + (size_t)brow * 768;
  }
  const __hip_bfloat16* Bsrc = isKV ? Bkv : (Bq + (size_t)n * 64 * 768);
  const int BROWS = isKV ? 128 : 64;        // B panel rows (cols of output)
  const int NACC = isKV ? 4 : 2;

  f32x16 acc[4] = {};

  const int lrow16 = lane >> 4, lslot16 = lane & 15;   // A staging decode
  const int lrow8  = lane >> 3, lslot8  = lane & 7;    // B staging decode

  for (int kk = 0; kk < 12; ++kk) {
    // ---- stage A: wave w stages rows [w*32, w*32+32), 8 gll x 4 rows ----
#pragma unroll
    for (int j = 0; j < 8; ++j) {
      int row0 = w * 32 + j * 4;
      int row = row0 + lrow16;
      int gs = lslot16 ^ (row & 15);
      const float* src = Asrc + (size_t)row * 768 + kk * 64 + gs * 4;
#if HAS_GLL
      gll16(src, &As[row0 * 64]);
#else
      *(f32x4*)(&As[row0 * 64] + lane * 4) = *(const f32x4*)src;
#endif
    }
    // ---- stage B: BROWS rows split over 4 waves, gll x 8 rows each ----
    {
      int perw = BROWS / 4;                 // 32 (KV) or 16 (Q)
#pragma unroll
      for (int j = 0; j < 4; ++j) {
        if (j * 8 < perw) {
          int c0 = w * perw + j * 8;
          int c = c0 + lrow8;
          const __hip_bfloat16* src = Bsrc + (size_t)c * 768 + kk * 64 + lslot8 * 8;
#if HAS_GLL
          gll16(src, &Bs[c0 * 64]);
#else
          *(u32x4*)(&Bs[c0 * 64] + lane * 8) = *(const u32x4*)src;
#endif
        }
      }
    }
    __syncthreads();   // drains vmcnt + barrier (m97 semantics)

    // ---- compute chunk kk (vmem-free) ----
    {
      const int row = w * 32 + cl;
#pragma unroll
      for (int ks = 0; ks < 4; ++ks) {
        int t = ks * 4 + hi * 2;
        f32x4 a0 = *(const f32x4*)&As[row * 64 + ((t       ^ (row & 15)) * 4)];
        f32x4 a1 = *(const f32x4*)&As[row * 64 + (((t + 1) ^ (row & 15)) * 4)];
        u32x4 a = {pkbf(a0.x, a0.y), pkbf(a0.z, a0.w), pkbf(a1.x, a1.y), pkbf(a1.z, a1.w)};
        int u0 = ks * 2 + hi;
#pragma unroll
        for (int g = 0; g < 4; ++g) {
          if (g < NACC) {
            int c = g * 32 + cl;
            u32x4 b = *(const u32x4*)&Bs[c * 64 + ((u0 ^ (c & 7)) * 8)];
            acc[g] = mfma32(a, b, acc[g]);
          }
        }
      }
    }
    __syncthreads();   // protect single buffer before next stage
  }

  if (isKV) {
    // K store: acc0/acc1 = K heads 0/1 (head-split rows of 64B)
    {
      const size_t base0 = (size_t)(nb * 2 + 0) * SS;
      const size_t base1 = (size_t)(nb * 2 + 1) * SS;
#pragma unroll
      for (int r = 0; r < 16; ++r) {
        int rl = (r & 3) + 8 * (r >> 2) + 4 * hi;
        int s  = s0 + w * 32 + rl;
        Kh[(base0 + s) * 32 + cl] = __float2bfloat16(acc[0][r]);
        Kh[(base1 + s) * 32 + cl] = __float2bfloat16(acc[1][r]);
      }
    }
    // V store: acc2/acc3 = V heads 0/1 -> Vt2[nb][h][sb][c][8]
#pragma unroll
    for (int k = 0; k < 4; ++k) {
      int sb = (s0 + w * 32 + 8 * k) >> 3;
      size_t A0 = (((size_t)(nb * 2 + 0) * (SS / 8) + sb) * 32 + cl) * 8 + 4 * hi;
      size_t A1 = (((size_t)(nb * 2 + 1) * (SS / 8) + sb) * 32 + cl) * 8 + 4 * hi;
      *(uint2*)(Vt2 + A0) = uint2{pkbf(acc[2][4*k], acc[2][4*k+1]), pkbf(acc[2][4*k+2], acc[2][4*k+3])};
      *(uint2*)(Vt2 + A1) = uint2{pkbf(acc[3][4*k], acc[3][4*k+1]), pkbf(acc[3][4*k+2], acc[3][4*k+3])};
    }
  } else {
#pragma unroll
    for (int r = 0; r < 16; ++r) {
      int rl = (r & 3) + 8 * (r >> 2) + 4 * hi;
      size_t rb = (size_t)(brow + w * 32 + rl) * 64;
      Qo[rb + cl]      = __float2bfloat16(acc[0][r]);
      Qo[rb + 32 + cl] = __float2bfloat16(acc[1][r]);
    }
  }
}

// ---------------------------------------------------------------------------
// Flash attention, split-S by 4 (proven: NSPLIT=8 regressed in round 15).
// Block = 4 waves sharing one (n,b,h,split); lockstep K/V streams
// (L1 broadcast), no LDS.
// ---------------------------------------------------------------------------
struct KV { u32x4 k0, k1, k2, k3, v0, v1, v2, v3; };

__global__ __launch_bounds__(256) void attn_kernel(
    const __hip_bfloat16* __restrict__ Q, const __hip_bfloat16* __restrict__ Kh,
    const __hip_bfloat16* __restrict__ Vt2, const float* __restrict__ bias2,
    __hip_bfloat16* __restrict__ Op, float* __restrict__ Mp, float* __restrict__ Lp)
{
  const int tid = threadIdx.x;
  const int lane = tid & 63, w = tid >> 6;
  const int cl = lane & 31, hi = lane >> 5;
  const int bid = blockIdx.x;
  const int g = bid % 48;            // (n,b,h) group -> fixed XCD (48 % 8 == 0)
  const int rest = bid / 48;         // 0..31
  const int sp = rest >> 3;          // split 0..3
  const int tq = rest & 7;           // q super-tile 0..7
  const int qtile = tq * 4 + w;      // 0..31
  const int h = g & 1, nb = g >> 1;
  const int b = nb & 3;
  const int qrow = nb * TT + qtile * 32;
  const int sbase = sp * (SS / NSPLIT);   // 768 keys per split

  const __hip_bfloat16* Qp = Q + (size_t)(qrow + cl) * 64 + h * 32 + hi * 8;
  u32x4 qf0 = *(const u32x4*)Qp;
  u32x4 qf1 = *(const u32x4*)(Qp + 16);

  const __hip_bfloat16* Kp = Kh + ((size_t)(nb * 2 + h) * SS + sbase) * 32;
  const __hip_bfloat16* Vp = Vt2 + (size_t)(nb * 2 + h) * SS * 32 + (size_t)sbase * 32;
  const float* Bp = bias2 + b * SS + sbase + hi * 4;

  const float scale2 = 0.17677669529663687f * 1.4426950408889634f;
  const f32x2 sc2 = {scale2, scale2};

  f32x16 ot = {};
  float m = -1e30f, lsum = 0.f;

  auto loadKV = [&](int it) {
    KV t;
    const __hip_bfloat16* kp = Kp + (size_t)it * 64 * 32;
    t.k0 = *(const u32x4*)(kp + cl * 32 + hi * 8);
    t.k1 = *(const u32x4*)(kp + cl * 32 + 16 + hi * 8);
    t.k2 = *(const u32x4*)(kp + 1024 + cl * 32 + hi * 8);
    t.k3 = *(const u32x4*)(kp + 1024 + cl * 32 + 16 + hi * 8);
    const __hip_bfloat16* vp = Vp + (size_t)it * 64 * 32;
    t.v0 = *(const u32x4*)(vp + ((0 * 2 + hi) * 32 + cl) * 8);
    t.v1 = *(const u32x4*)(vp + ((1 * 2 + hi) * 32 + cl) * 8);
    t.v2 = *(const u32x4*)(vp + ((2 * 2 + hi) * 32 + cl) * 8);
    t.v3 = *(const u32x4*)(vp + ((3 * 2 + hi) * 32 + cl) * 8);
    return t;
  };

  auto compute = [&](const KV& t, int it) {
    f32x16 pz0 = {}, pz1 = {};
    pz0 = mfma32(t.k0, qf0, pz0);
    pz0 = mfma32(t.k1, qf1, pz0);
    pz1 = mfma32(t.k2, qf0, pz1);
    pz1 = mfma32(t.k3, qf1, pz1);
    const float* bp = Bp + it * 64;
    f32x4 b4[8];
#pragma unroll
    for (int q = 0; q < 8; ++q) b4[q] = *(const f32x4*)(bp + 8 * q);
    f32x2 p2[16];
#pragma unroll
    for (int i = 0; i < 8; ++i) {
      f32x4 bq0 = b4[i >> 1];
      f32x4 bq1 = b4[4 + (i >> 1)];
      f32x2 bv0 = (i & 1) ? f32x2{bq0.z, bq0.w} : f32x2{bq0.x, bq0.y};
      f32x2 bv1 = (i & 1) ? f32x2{bq1.z, bq1.w} : f32x2{bq1.x, bq1.y};
      p2[i]     = f32x2{pz0[2*i], pz0[2*i+1]} * sc2 + bv0;
      p2[8 + i] = f32x2{pz1[2*i], pz1[2*i+1]} * sc2 + bv1;
    }
    f32x2 mx = p2[0];
#pragma unroll
    for (int i = 1; i < 16; ++i) {
      mx.x = fmaxf(mx.x, p2[i].x);
      mx.y = fmaxf(mx.y, p2[i].y);
    }
    float tm = fmaxf(mx.x, mx.y);
    tm = fmaxf(tm, __shfl_xor(tm, 32));
    if (!__all(tm - m <= 8.f)) {       // defer-max
      float mn = fmaxf(m, tm);
      float f = exp2f(m - mn);
#pragma unroll
      for (int i = 0; i < 16; ++i) ot[i] *= f;
      lsum *= f;
      m = mn;
    }
    const f32x2 m2 = {m, m};
    f32x2 s2 = {0.f, 0.f};
#pragma unroll
    for (int i = 0; i < 16; ++i) {
      f32x2 d = p2[i] - m2;
      f32x2 e = {exp2f(d.x), exp2f(d.y)};
      p2[i] = e;
      s2 += e;
    }
    float ts = s2.x + s2.y;
    ts += __shfl_xor(ts, 32);
    lsum += ts;
    // P -> bf16 B-frags via permlane32_swap
    uint cv[16];
#pragma unroll
    for (int i = 0; i < 16; ++i) cv[i] = pkbf(p2[i].x, p2[i].y);
    u32x4 pf0, pf1, pf2, pf3;
    {
      uint x0, y0, x1, y1;
      plswap(cv[0], cv[2],  x0, y0); plswap(cv[1], cv[3],  x1, y1);
      pf0 = u32x4{x0, x1, y0, y1};
      plswap(cv[4], cv[6],  x0, y0); plswap(cv[5], cv[7],  x1, y1);
      pf1 = u32x4{x0, x1, y0, y1};
      plswap(cv[8], cv[10], x0, y0); plswap(cv[9], cv[11], x1, y1);
      pf2 = u32x4{x0, x1, y0, y1};
      plswap(cv[12], cv[14], x0, y0); plswap(cv[13], cv[15], x1, y1);
      pf3 = u32x4{x0, x1, y0, y1};
    }
    ot = mfma32(t.v0, pf0, ot);
    ot = mfma32(t.v1, pf1, ot);
    ot = mfma32(t.v2, pf2, ot);
    ot = mfma32(t.v3, pf3, ot);
  };

  KV cur = loadKV(0);
#pragma unroll 1
  for (int it = 0; it < NITER; ++it) {
    KV nxt = loadKV(it + 1 < NITER ? it + 1 : NITER - 1);
    compute(cur, it);
    cur = nxt;
    __builtin_amdgcn_s_barrier();   // keep the 4 waves' K/V streams in lockstep (L1 reuse)
  }

  // store unnormalized O^T partial (bf16) + m/l
  __hip_bfloat16* op = Op + ((size_t)sp * NROW + qrow + cl) * 64 + h * 32 + 4 * hi;
#pragma unroll
  for (int k = 0; k < 4; ++k) {
    uint2 wv = {pkbf(ot[4*k], ot[4*k+1]), pkbf(ot[4*k+2], ot[4*k+3])};
    *(uint2*)(op + 8 * k) = wv;
  }
  if (lane < 32) {
    int mi = ((sp * 24 + nb) * 2 + h) * TT + qtile * 32 + cl;
    Mp[mi] = m;
    Lp[mi] = lsum;
  }
}

// ---------------------------------------------------------------------------
// Fused split-combine + out-projection (MFMA) + residual + LayerNorm.
// Block 256 = 4 waves, 32 rows; wave w owns cols [w*192, +192).
// ---------------------------------------------------------------------------
__global__ __launch_bounds__(256) void oproj_ln_kernel(
    const float* __restrict__ x, const __hip_bfloat16* __restrict__ Op,
    const float* __restrict__ Mp, const float* __restrict__ Lp,
    const __hip_bfloat16* __restrict__ Bo, const float* __restrict__ gamma,
    const float* __restrict__ beta, float* __restrict__ out)
{
  __shared__ float red[4][32][2];
  __shared__ float redf[32][2];
  const int tid = threadIdx.x;
  const int lane = tid & 63, w = tid >> 6;
  const int cl = lane & 31, hi = lane >> 5;
  const int row0 = blockIdx.x * 32;
  const int n = row0 >> 12;
  const int nb = row0 >> 10;
  const int trow = (row0 & 1023) + cl;
  const int MLS = 24 * 2 * TT;

  // combine weights per head
  float wsp[2][NSPLIT];
#pragma unroll
  for (int h = 0; h < 2; ++h) {
    int mi = (nb * 2 + h) * TT + trow;
    float mv[NSPLIT], lv[NSPLIT];
#pragma unroll
    for (int sp = 0; sp < NSPLIT; ++sp) { mv[sp] = Mp[mi + sp * MLS]; lv[sp] = Lp[mi + sp * MLS]; }
    float ms = mv[0];
#pragma unroll
    for (int sp = 1; sp < NSPLIT; ++sp) ms = fmaxf(ms, mv[sp]);
    float den = 0.f;
#pragma unroll
    for (int sp = 0; sp < NSPLIT; ++sp) { wsp[h][sp] = exp2f(mv[sp] - ms); den = fmaf(lv[sp], wsp[h][sp], den); }
    float inv = 1.0f / den;
#pragma unroll
    for (int sp = 0; sp < NSPLIT; ++sp) wsp[h][sp] *= inv;
  }

  // A-frags: combine partials
  u32x4 af[4];
#pragma unroll
  for (int ks = 0; ks < 4; ++ks) {
    int h = ks >> 1;
    size_t off = (size_t)(row0 + cl) * 64 + ks * 16 + hi * 8;
    f32x2 s0 = {}, s1 = {}, s2 = {}, s3 = {};
#pragma unroll
    for (int sp = 0; sp < NSPLIT; ++sp) {
      u32x4 v = *(const u32x4*)(Op + (size_t)sp * NROW * 64 + off);
      float wv = wsp[h][sp];
      s0 += f32x2{b2f(v[0] & 0xffffu), b2f(v[0] >> 16)} * wv;
      s1 += f32x2{b2f(v[1] & 0xffffu), b2f(v[1] >> 16)} * wv;
      s2 += f32x2{b2f(v[2] & 0xffffu), b2f(v[2] >> 16)} * wv;
      s3 += f32x2{b2f(v[3] & 0xffffu), b2f(v[3] >> 16)} * wv;
    }
    af[ks] = u32x4{pkbf(s0.x, s0.y), pkbf(s1.x, s1.y), pkbf(s2.x, s2.y), pkbf(s3.x, s3.y)};
  }

  const __hip_bfloat16* Bp = Bo + ((size_t)n * 768 + w * 192 + cl) * 64 + hi * 8;
  f32x16 acc[6] = {};
#pragma unroll
  for (int ks = 0; ks < 4; ++ks) {
#pragma unroll
    for (int t = 0; t < 6; ++t) {
      u32x4 bb = *(const u32x4*)(Bp + (size_t)(t * 32) * 64 + ks * 16);
      acc[t] = mfma32(af[ks], bb, acc[t]);
    }
  }

  float s1[16], s2[16];
#pragma unroll
  for (int r = 0; r < 16; ++r) { s1[r] = 0.f; s2[r] = 0.f; }
#pragma unroll
  for (int t = 0; t < 6; ++t) {
#pragma unroll
    for (int r = 0; r < 16; ++r) {
      int R = (r & 3) + 8 * (r >> 2) + 4 * hi;
      int col = w * 192 + t * 32 + cl;
      float y = acc[t][r] + x[(size_t)(row0 + R) * 768 + col];
      acc[t][r] = y;
      s1[r] += y;
      s2[r] = fmaf(y, y, s2[r]);
    }
  }
#pragma unroll
  for (int r = 0; r < 16; ++r) {
#pragma unroll
    for (int off = 1; off < 32; off <<= 1) {
      s1[r] += __shfl_xor(s1[r], off);
      s2[r] += __shfl_xor(s2[r], off);
    }
  }
  if (cl == 0) {
#pragma unroll
    for (int r = 0; r < 16; ++r) {
      int R = (r & 3) + 8 * (r >> 2) + 4 * hi;
      red[w][R][0] = s1[r];
      red[w][R][1] = s2[r];
    }
  }
  __syncthreads();
  if (tid < 64) {
    int R = tid & 31, st = tid >> 5;
    redf[R][st] = red[0][R][st] + red[1][R][st] + red[2][R][st] + red[3][R][st];
  }
  __syncthreads();

  float gv[6], bv[6];
#pragma unroll
  for (int t = 0; t < 6; ++t) {
    int col = w * 192 + t * 32 + cl;
    gv[t] = gamma[n * 768 + col];
    bv[t] = beta[n * 768 + col];
  }
#pragma unroll
  for (int r = 0; r < 16; ++r) {
    int R = (r & 3) + 8 * (r >> 2) + 4 * hi;
    float mu = redf[R][0] * (1.0f / 768.0f);
    float var = redf[R][1] * (1.0f / 768.0f) - mu * mu;
    float rs = rsqrtf(var + LNEPS);
#pragma unroll
    for (int t = 0; t < 6; ++t) {
      int col = w * 192 + t * 32 + cl;
      out[(size_t)(row0 + R) * 768 + col] = (acc[t][r] - mu) * rs * gv[t] + bv[t];
    }
  }
}

// ---------------------------------------------------------------------------
extern "C" void kernel_launch(void* const* d_in, const int* in_sizes, int n_in,
                              void* d_out, int out_size, void* d_ws, size_t ws_size,
                              hipStream_t stream) {
  const float* x     = (const float*)d_in[0];
  const float* hist  = (const float*)d_in[1];
  const int*   mask  = (const int*)d_in[2];
  const float* Wq    = (const float*)d_in[3];
  const float* Wk    = (const float*)d_in[4];
  const float* Wv    = (const float*)d_in[5];
  const float* Wo    = (const float*)d_in[6];
  const float* gamma = (const float*)d_in[7];
  const float* beta  = (const float*)d_in[8];
  float* out = (float*)d_out;

  char* ws = (char*)d_ws;
  __hip_bfloat16* Qb  = (__hip_bfloat16*)ws;  ws += (size_t)NROW * II * 2;
  __hip_bfloat16* Kh  = (__hip_bfloat16*)ws;  ws += (size_t)NKVROW * II * 2;
  __hip_bfloat16* Vt2 = (__hip_bfloat16*)ws;  ws += (size_t)NKVROW * II * 2;
  __hip_bfloat16* Op  = (__hip_bfloat16*)ws;  ws += (size_t)NSPLIT * NROW * II * 2;
  float* Mp           = (float*)ws;           ws += (size_t)NSPLIT * 24 * 2 * TT * 4;
  float* Lp           = (float*)ws;           ws += (size_t)NSPLIT * 24 * 2 * TT * 4;
  __hip_bfloat16* Bkv = (__hip_bfloat16*)ws;  ws += (size_t)128 * 768 * 2;
  __hip_bfloat16* Bq  = (__hip_bfloat16*)ws;  ws += (size_t)NDOM * 64 * 768 * 2;
  __hip_bfloat16* Bo  = (__hip_bfloat16*)ws;  ws += (size_t)NDOM * 768 * 64 * 2;
  float* bias2        = (float*)ws;           ws += (size_t)BB * SS * 4;

  const int PREP_N = 128*768 + NDOM*64*768 + NDOM*768*64 + BB*SS;
  prep_kernel<<<(PREP_N + 255) / 256, 256, 0, stream>>>(mask, Wk, Wv, Wq, Wo, Bkv, Bq, Bo, bias2);
  qkv_gemm_kernel<<<NKVB + NQB, 256, 0, stream>>>(x, hist, Bkv, Bq, Qb, Kh, Vt2);
  attn_kernel<<<48 * 8 * NSPLIT, 256, 0, stream>>>(Qb, Kh, Vt2, bias2, Op, Mp, Lp);
  oproj_ln_kernel<<<NROW / 32, 256, 0, stream>>>(x, Op, Mp, Lp, Bo, gamma, beta, out);
}

// Round 18
// 196.532 us; speedup vs baseline: 1.0697x; 1.0220x over previous
//
#include <hip/hip_runtime.h>
#include <hip/hip_bf16.h>
#include <math.h>

#define NDOM 6
#define BB 4
#define TT 1024
#define DD 768
#define PP 3
#define HH 2
#define DHH 32
#define II 64
#define SS (PP*TT)        // 3072
#define NROW (NDOM*BB*TT) // 24576
#define NKVROW (NDOM*BB*SS)
#define NSPLIT 4
#define NITER (SS/NSPLIT/64)   // 12
#define NKVB (NKVROW/128) // 576
#define NQB  (NROW/128)   // 192
#define LNEPS 1e-5f

typedef unsigned int uint;
typedef uint  u32x4  __attribute__((ext_vector_type(4)));
typedef int   i32x2  __attribute__((ext_vector_type(2)));
typedef float f32x2  __attribute__((ext_vector_type(2)));
typedef float f32x4  __attribute__((ext_vector_type(4)));
typedef float f32x16 __attribute__((ext_vector_type(16)));
typedef __bf16 bf16x8 __attribute__((ext_vector_type(8)));

// D = A(32x16) * B(16x32) + C.  A row = lane&31, k = (lane>>5)*8+j.
// B col = lane&31, k = (lane>>5)*8+j.  D: col = lane&31, row=(r&3)+8*(r>>2)+4*(lane>>5).
__device__ __forceinline__ f32x16 mfma32(u32x4 a, u32x4 b, f32x16 c) {
  return __builtin_amdgcn_mfma_f32_32x32x16_bf16(
      __builtin_bit_cast(bf16x8, a), __builtin_bit_cast(bf16x8, b), c, 0, 0, 0);
}

__device__ __forceinline__ uint pkbf(float a, float b) {
  union { __bf16 h[2]; uint u; } v;
  v.h[0] = (__bf16)a; v.h[1] = (__bf16)b;
  return v.u;
}
__device__ __forceinline__ float b2f(uint u16) {
  union { uint i; float f; } v; v.i = u16 << 16; return v.f;
}

// x gets {a_lo | partner's b}, y gets {partner's a | b}  (32-lane halves)
__device__ __forceinline__ void plswap(uint a, uint b, uint& x, uint& y) {
#if __has_builtin(__builtin_amdgcn_permlane32_swap)
  i32x2 r = __builtin_amdgcn_permlane32_swap((int)a, (int)b, false, false);
  x = (uint)r.x; y = (uint)r.y;
#else
  uint sa = __shfl_xor(a, 32), sb = __shfl_xor(b, 32);
  bool h1 = (threadIdx.x & 32) != 0;
  x = h1 ? sb : a;
  y = h1 ? b : sa;
#endif
}

// async global->LDS, 16B per lane.  LDS dest = wave-uniform base + lane*16.
#if __has_builtin(__builtin_amdgcn_global_load_lds)
#define HAS_GLL 1
typedef __attribute__((address_space(3))) uint lds_u32;
typedef __attribute__((address_space(1))) uint glb_u32;
__device__ __forceinline__ void gll16(const void* src, void* lds_base) {
  __builtin_amdgcn_global_load_lds((const glb_u32*)src, (lds_u32*)lds_base, 16, 0, 0);
}
#else
#define HAS_GLL 0
#endif

// ---------------------------------------------------------------------------
// Prep: bf16 transposed weights (B-side pre-XOR-swizzled within each 64-k
// chunk so a LINEAR global_load_lds yields LDS[c][u] = B[c][u^(c&7)]),
// Bo row-major, exp2-domain mask bias.   (round-14 proven layout)
// ---------------------------------------------------------------------------
__global__ __launch_bounds__(256) void prep_kernel(
    const int* __restrict__ mask, const float* __restrict__ Wk,
    const float* __restrict__ Wv, const float* __restrict__ Wq,
    const float* __restrict__ Wo,
    __hip_bfloat16* __restrict__ Bkv, __hip_bfloat16* __restrict__ Bq,
    __hip_bfloat16* __restrict__ Bo, float* __restrict__ bias2)
{
  int i = blockIdx.x * 256 + threadIdx.x;
  const int N1 = 128 * 768;          // Bkv (swizzled)
  const int N2 = NDOM * 64 * 768;    // Bq  (swizzled)
  const int N3 = NDOM * 768 * 64;    // Bo
  if (i < N1) {
    int c = i / 768, kd = i % 768;
    int e = kd & 7, ud = (kd >> 3) & 7, kk = kd >> 6;
    int k = (kk << 6) + ((ud ^ (c & 7)) << 3) + e;
    float v = (c < 64) ? Wk[k * 64 + c] : Wv[k * 64 + (c - 64)];
    Bkv[i] = __float2bfloat16(v);
  } else if (i < N1 + N2) {
    int j = i - N1;
    int n = j / (64 * 768);
    int rem = j % (64 * 768);
    int c = rem / 768, kd = rem % 768;
    int e = kd & 7, ud = (kd >> 3) & 7, kk = kd >> 6;
    int k = (kk << 6) + ((ud ^ (c & 7)) << 3) + e;
    Bq[j] = __float2bfloat16(Wq[((size_t)n * 768 + k) * 64 + c]);
  } else if (i < N1 + N2 + N3) {
    int j = i - N1 - N2;
    int n = j / (768 * 64);
    int rem = j % (768 * 64);
    int d = rem / 64, k = rem % 64;
    Bo[j] = __float2bfloat16(Wo[((size_t)n * 64 + k) * 768 + d]);
  } else if (i < N1 + N2 + N3 + BB * SS) {
    int j = i - N1 - N2 - N3;
    int b = j / SS, s = j % SS;
    bias2[j] = (1.0f - (float)mask[b * TT + (s & (TT - 1))]) * (-14426.950408889634f);
  }
}

// ---------------------------------------------------------------------------
// Fused Q + KV projection GEMM, m97 structure (round-14 PROVEN OPTIMUM of 8
// variants — do not restructure): BM=128, BK=64, BOTH operands staged per
// chunk via global_load_lds (contiguous 1KB/instr), single LDS buffer,
// sync -> vmem-free compute (ds_read + cvt_pk + MFMA) -> sync.
// ---------------------------------------------------------------------------
__global__ __launch_bounds__(256) void qkv_gemm_kernel(
    const float* __restrict__ x, const float* __restrict__ hist,
    const __hip_bfloat16* __restrict__ Bkv, const __hip_bfloat16* __restrict__ Bq,
    __hip_bfloat16* __restrict__ Qo, __hip_bfloat16* __restrict__ Kh,
    __hip_bfloat16* __restrict__ Vt2)
{
  __shared__ float As[128 * 64];            // 32 KB
  __shared__ __hip_bfloat16 Bs[128 * 64];   // 16 KB
  const int tid = threadIdx.x;
  const int lane = tid & 63, w = tid >> 6;
  const int cl = lane & 31, hi = lane >> 5;

  const bool isKV = blockIdx.x < NKVB;
  const float* Asrc;
  int nb = 0, s0 = 0, n = 0, brow = 0;
  if (isKV) {
    brow = blockIdx.x * 128;
    nb = brow / SS; n = nb >> 2;
    int b = nb & 3;
    s0 = brow % SS;
    int p = s0 / TT, t0 = s0 % TT;          // 128 | 1024: block stays in one p
    Asrc = hist + (((size_t)(p * NDOM + n) * BB + b) * TT + t0) * 768;
  } else {
    brow = (blockIdx.x - NKVB) * 128;
    n = brow >> 12;
    Asrc = x + (size_t)brow * 768;
  }
  const __hip_bfloat16* Bsrc = isKV ? Bkv : (Bq + (size_t)n * 64 * 768);
  const int BROWS = isKV ? 128 : 64;        // B panel rows (cols of output)
  const int NACC = isKV ? 4 : 2;

  f32x16 acc[4] = {};

  const int lrow16 = lane >> 4, lslot16 = lane & 15;   // A staging decode
  const int lrow8  = lane >> 3, lslot8  = lane & 7;    // B staging decode

  for (int kk = 0; kk < 12; ++kk) {
    // ---- stage A: wave w stages rows [w*32, w*32+32), 8 gll x 4 rows ----
#pragma unroll
    for (int j = 0; j < 8; ++j) {
      int row0 = w * 32 + j * 4;
      int row = row0 + lrow16;
      int gs = lslot16 ^ (row & 15);
      const float* src = Asrc + (size_t)row * 768 + kk * 64 + gs * 4;
#if HAS_GLL
      gll16(src, &As[row0 * 64]);
#else
      *(f32x4*)(&As[row0 * 64] + lane * 4) = *(const f32x4*)src;
#endif
    }
    // ---- stage B: BROWS rows split over 4 waves, gll x 8 rows each ----
    {
      int perw = BROWS / 4;                 // 32 (KV) or 16 (Q)
#pragma unroll
      for (int j = 0; j < 4; ++j) {
        if (j * 8 < perw) {
          int c0 = w * perw + j * 8;
          int c = c0 + lrow8;
          const __hip_bfloat16* src = Bsrc + (size_t)c * 768 + kk * 64 + lslot8 * 8;
#if HAS_GLL
          gll16(src, &Bs[c0 * 64]);
#else
          *(u32x4*)(&Bs[c0 * 64] + lane * 8) = *(const u32x4*)src;
#endif
        }
      }
    }
    __syncthreads();   // drains vmcnt + barrier (m97 semantics)

    // ---- compute chunk kk (vmem-free) ----
    {
      const int row = w * 32 + cl;
#pragma unroll
      for (int ks = 0; ks < 4; ++ks) {
        int t = ks * 4 + hi * 2;
        f32x4 a0 = *(const f32x4*)&As[row * 64 + ((t       ^ (row & 15)) * 4)];
        f32x4 a1 = *(const f32x4*)&As[row * 64 + (((t + 1) ^ (row & 15)) * 4)];
        u32x4 a = {pkbf(a0.x, a0.y), pkbf(a0.z, a0.w), pkbf(a1.x, a1.y), pkbf(a1.z, a1.w)};
        int u0 = ks * 2 + hi;
#pragma unroll
        for (int g = 0; g < 4; ++g) {
          if (g < NACC) {
            int c = g * 32 + cl;
            u32x4 b = *(const u32x4*)&Bs[c * 64 + ((u0 ^ (c & 7)) * 8)];
            acc[g] = mfma32(a, b, acc[g]);
          }
        }
      }
    }
    __syncthreads();   // protect single buffer before next stage
  }

  if (isKV) {
    // K store: acc0/acc1 = K heads 0/1 (head-split rows of 64B)
    {
      const size_t base0 = (size_t)(nb * 2 + 0) * SS;
      const size_t base1 = (size_t)(nb * 2 + 1) * SS;
#pragma unroll
      for (int r = 0; r < 16; ++r) {
        int rl = (r & 3) + 8 * (r >> 2) + 4 * hi;
        int s  = s0 + w * 32 + rl;
        Kh[(base0 + s) * 32 + cl] = __float2bfloat16(acc[0][r]);
        Kh[(base1 + s) * 32 + cl] = __float2bfloat16(acc[1][r]);
      }
    }
    // V store: acc2/acc3 = V heads 0/1 -> Vt2[nb][h][sb][c][8]
#pragma unroll
    for (int k = 0; k < 4; ++k) {
      int sb = (s0 + w * 32 + 8 * k) >> 3;
      size_t A0 = (((size_t)(nb * 2 + 0) * (SS / 8) + sb) * 32 + cl) * 8 + 4 * hi;
      size_t A1 = (((size_t)(nb * 2 + 1) * (SS / 8) + sb) * 32 + cl) * 8 + 4 * hi;
      *(uint2*)(Vt2 + A0) = uint2{pkbf(acc[2][4*k], acc[2][4*k+1]), pkbf(acc[2][4*k+2], acc[2][4*k+3])};
      *(uint2*)(Vt2 + A1) = uint2{pkbf(acc[3][4*k], acc[3][4*k+1]), pkbf(acc[3][4*k+2], acc[3][4*k+3])};
    }
  } else {
#pragma unroll
    for (int r = 0; r < 16; ++r) {
      int rl = (r & 3) + 8 * (r >> 2) + 4 * hi;
      size_t rb = (size_t)(brow + w * 32 + rl) * 64;
      Qo[rb + cl]      = __float2bfloat16(acc[0][r]);
      Qo[rb + 32 + cl] = __float2bfloat16(acc[1][r]);
    }
  }
}

// ---------------------------------------------------------------------------
// Flash attention, split-S by 4.  Block = 4 waves on one (n,b,h,split);
// wave w owns q-tile tq*4+w.  ABLATION (this round): per-iteration lockstep
// s_barrier REMOVED — waves free-run; K/V tile reuse window is short enough
// that L1 still serves most broadcasts, and stragglers no longer serialize.
// ---------------------------------------------------------------------------
struct KV { u32x4 k0, k1, k2, k3, v0, v1, v2, v3; };

__global__ __launch_bounds__(256) void attn_kernel(
    const __hip_bfloat16* __restrict__ Q, const __hip_bfloat16* __restrict__ Kh,
    const __hip_bfloat16* __restrict__ Vt2, const float* __restrict__ bias2,
    __hip_bfloat16* __restrict__ Op, float* __restrict__ Mp, float* __restrict__ Lp)
{
  const int tid = threadIdx.x;
  const int lane = tid & 63, w = tid >> 6;
  const int cl = lane & 31, hi = lane >> 5;
  const int bid = blockIdx.x;
  const int g = bid % 48;            // (n,b,h) group -> fixed XCD (48 % 8 == 0)
  const int rest = bid / 48;         // 0..31
  const int sp = rest >> 3;          // split 0..3
  const int tq = rest & 7;           // q super-tile 0..7
  const int qtile = tq * 4 + w;      // 0..31
  const int h = g & 1, nb = g >> 1;
  const int b = nb & 3;
  const int qrow = nb * TT + qtile * 32;
  const int sbase = sp * (SS / NSPLIT);   // 768 keys per split

  const __hip_bfloat16* Qp = Q + (size_t)(qrow + cl) * 64 + h * 32 + hi * 8;
  u32x4 qf0 = *(const u32x4*)Qp;
  u32x4 qf1 = *(const u32x4*)(Qp + 16);

  const __hip_bfloat16* Kp = Kh + ((size_t)(nb * 2 + h) * SS + sbase) * 32;
  const __hip_bfloat16* Vp = Vt2 + (size_t)(nb * 2 + h) * SS * 32 + (size_t)sbase * 32;
  const float* Bp = bias2 + b * SS + sbase + hi * 4;

  const float scale2 = 0.17677669529663687f * 1.4426950408889634f;
  const f32x2 sc2 = {scale2, scale2};

  f32x16 ot = {};
  float m = -1e30f, lsum = 0.f;

  auto loadKV = [&](int it) {
    KV t;
    const __hip_bfloat16* kp = Kp + (size_t)it * 64 * 32;
    t.k0 = *(const u32x4*)(kp + cl * 32 + hi * 8);
    t.k1 = *(const u32x4*)(kp + cl * 32 + 16 + hi * 8);
    t.k2 = *(const u32x4*)(kp + 1024 + cl * 32 + hi * 8);
    t.k3 = *(const u32x4*)(kp + 1024 + cl * 32 + 16 + hi * 8);
    const __hip_bfloat16* vp = Vp + (size_t)it * 64 * 32;
    t.v0 = *(const u32x4*)(vp + ((0 * 2 + hi) * 32 + cl) * 8);
    t.v1 = *(const u32x4*)(vp + ((1 * 2 + hi) * 32 + cl) * 8);
    t.v2 = *(const u32x4*)(vp + ((2 * 2 + hi) * 32 + cl) * 8);
    t.v3 = *(const u32x4*)(vp + ((3 * 2 + hi) * 32 + cl) * 8);
    return t;
  };

  auto compute = [&](const KV& t, int it) {
    f32x16 pz0 = {}, pz1 = {};
    pz0 = mfma32(t.k0, qf0, pz0);
    pz0 = mfma32(t.k1, qf1, pz0);
    pz1 = mfma32(t.k2, qf0, pz1);
    pz1 = mfma32(t.k3, qf1, pz1);
    const float* bp = Bp + it * 64;
    f32x4 b4[8];
#pragma unroll
    for (int q = 0; q < 8; ++q) b4[q] = *(const f32x4*)(bp + 8 * q);
    f32x2 p2[16];
#pragma unroll
    for (int i = 0; i < 8; ++i) {
      f32x4 bq0 = b4[i >> 1];
      f32x4 bq1 = b4[4 + (i >> 1)];
      f32x2 bv0 = (i & 1) ? f32x2{bq0.z, bq0.w} : f32x2{bq0.x, bq0.y};
      f32x2 bv1 = (i & 1) ? f32x2{bq1.z, bq1.w} : f32x2{bq1.x, bq1.y};
      p2[i]     = f32x2{pz0[2*i], pz0[2*i+1]} * sc2 + bv0;
      p2[8 + i] = f32x2{pz1[2*i], pz1[2*i+1]} * sc2 + bv1;
    }
    f32x2 mx = p2[0];
#pragma unroll
    for (int i = 1; i < 16; ++i) {
      mx.x = fmaxf(mx.x, p2[i].x);
      mx.y = fmaxf(mx.y, p2[i].y);
    }
    float tm = fmaxf(mx.x, mx.y);
    tm = fmaxf(tm, __shfl_xor(tm, 32));
    if (!__all(tm - m <= 8.f)) {       // defer-max
      float mn = fmaxf(m, tm);
      float f = exp2f(m - mn);
#pragma unroll
      for (int i = 0; i < 16; ++i) ot[i] *= f;
      lsum *= f;
      m = mn;
    }
    const f32x2 m2 = {m, m};
    f32x2 s2 = {0.f, 0.f};
#pragma unroll
    for (int i = 0; i < 16; ++i) {
      f32x2 d = p2[i] - m2;
      f32x2 e = {exp2f(d.x), exp2f(d.y)};
      p2[i] = e;
      s2 += e;
    }
    float ts = s2.x + s2.y;
    ts += __shfl_xor(ts, 32);
    lsum += ts;
    // P -> bf16 B-frags via permlane32_swap
    uint cv[16];
#pragma unroll
    for (int i = 0; i < 16; ++i) cv[i] = pkbf(p2[i].x, p2[i].y);
    u32x4 pf0, pf1, pf2, pf3;
    {
      uint x0, y0, x1, y1;
      plswap(cv[0], cv[2],  x0, y0); plswap(cv[1], cv[3],  x1, y1);
      pf0 = u32x4{x0, x1, y0, y1};
      plswap(cv[4], cv[6],  x0, y0); plswap(cv[5], cv[7],  x1, y1);
      pf1 = u32x4{x0, x1, y0, y1};
      plswap(cv[8], cv[10], x0, y0); plswap(cv[9], cv[11], x1, y1);
      pf2 = u32x4{x0, x1, y0, y1};
      plswap(cv[12], cv[14], x0, y0); plswap(cv[13], cv[15], x1, y1);
      pf3 = u32x4{x0, x1, y0, y1};
    }
    ot = mfma32(t.v0, pf0, ot);
    ot = mfma32(t.v1, pf1, ot);
    ot = mfma32(t.v2, pf2, ot);
    ot = mfma32(t.v3, pf3, ot);
  };

  KV cur = loadKV(0);
#pragma unroll 1
  for (int it = 0; it < NITER; ++it) {
    KV nxt = loadKV(it + 1 < NITER ? it + 1 : NITER - 1);
    compute(cur, it);
    cur = nxt;
  }

  // store unnormalized O^T partial (bf16) + m/l
  __hip_bfloat16* op = Op + ((size_t)sp * NROW + qrow + cl) * 64 + h * 32 + 4 * hi;
#pragma unroll
  for (int k = 0; k < 4; ++k) {
    uint2 wv = {pkbf(ot[4*k], ot[4*k+1]), pkbf(ot[4*k+2], ot[4*k+3])};
    *(uint2*)(op + 8 * k) = wv;
  }
  if (lane < 32) {
    int mi = ((sp * 24 + nb) * 2 + h) * TT + qtile * 32 + cl;
    Mp[mi] = m;
    Lp[mi] = lsum;
  }
}

// ---------------------------------------------------------------------------
// Fused split-combine + out-projection (MFMA) + residual + LayerNorm.
// Block 256 = 4 waves, 32 rows; wave w owns cols [w*192, +192).
// ---------------------------------------------------------------------------
__global__ __launch_bounds__(256) void oproj_ln_kernel(
    const float* __restrict__ x, const __hip_bfloat16* __restrict__ Op,
    const float* __restrict__ Mp, const float* __restrict__ Lp,
    const __hip_bfloat16* __restrict__ Bo, const float* __restrict__ gamma,
    const float* __restrict__ beta, float* __restrict__ out)
{
  __shared__ float red[4][32][2];
  __shared__ float redf[32][2];
  const int tid = threadIdx.x;
  const int lane = tid & 63, w = tid >> 6;
  const int cl = lane & 31, hi = lane >> 5;
  const int row0 = blockIdx.x * 32;
  const int n = row0 >> 12;
  const int nb = row0 >> 10;
  const int trow = (row0 & 1023) + cl;
  const int MLS = 24 * 2 * TT;

  // combine weights per head
  float wsp[2][NSPLIT];
#pragma unroll
  for (int h = 0; h < 2; ++h) {
    int mi = (nb * 2 + h) * TT + trow;
    float mv[NSPLIT], lv[NSPLIT];
#pragma unroll
    for (int sp = 0; sp < NSPLIT; ++sp) { mv[sp] = Mp[mi + sp * MLS]; lv[sp] = Lp[mi + sp * MLS]; }
    float ms = mv[0];
#pragma unroll
    for (int sp = 1; sp < NSPLIT; ++sp) ms = fmaxf(ms, mv[sp]);
    float den = 0.f;
#pragma unroll
    for (int sp = 0; sp < NSPLIT; ++sp) { wsp[h][sp] = exp2f(mv[sp] - ms); den = fmaf(lv[sp], wsp[h][sp], den); }
    float inv = 1.0f / den;
#pragma unroll
    for (int sp = 0; sp < NSPLIT; ++sp) wsp[h][sp] *= inv;
  }

  // A-frags: combine partials
  u32x4 af[4];
#pragma unroll
  for (int ks = 0; ks < 4; ++ks) {
    int h = ks >> 1;
    size_t off = (size_t)(row0 + cl) * 64 + ks * 16 + hi * 8;
    f32x2 s0 = {}, s1 = {}, s2 = {}, s3 = {};
#pragma unroll
    for (int sp = 0; sp < NSPLIT; ++sp) {
      u32x4 v = *(const u32x4*)(Op + (size_t)sp * NROW * 64 + off);
      float wv = wsp[h][sp];
      s0 += f32x2{b2f(v[0] & 0xffffu), b2f(v[0] >> 16)} * wv;
      s1 += f32x2{b2f(v[1] & 0xffffu), b2f(v[1] >> 16)} * wv;
      s2 += f32x2{b2f(v[2] & 0xffffu), b2f(v[2] >> 16)} * wv;
      s3 += f32x2{b2f(v[3] & 0xffffu), b2f(v[3] >> 16)} * wv;
    }
    af[ks] = u32x4{pkbf(s0.x, s0.y), pkbf(s1.x, s1.y), pkbf(s2.x, s2.y), pkbf(s3.x, s3.y)};
  }

  const __hip_bfloat16* Bp = Bo + ((size_t)n * 768 + w * 192 + cl) * 64 + hi * 8;
  f32x16 acc[6] = {};
#pragma unroll
  for (int ks = 0; ks < 4; ++ks) {
#pragma unroll
    for (int t = 0; t < 6; ++t) {
      u32x4 bb = *(const u32x4*)(Bp + (size_t)(t * 32) * 64 + ks * 16);
      acc[t] = mfma32(af[ks], bb, acc[t]);
    }
  }

  float s1[16], s2[16];
#pragma unroll
  for (int r = 0; r < 16; ++r) { s1[r] = 0.f; s2[r] = 0.f; }
#pragma unroll
  for (int t = 0; t < 6; ++t) {
#pragma unroll
    for (int r = 0; r < 16; ++r) {
      int R = (r & 3) + 8 * (r >> 2) + 4 * hi;
      int col = w * 192 + t * 32 + cl;
      float y = acc[t][r] + x[(size_t)(row0 + R) * 768 + col];
      acc[t][r] = y;
      s1[r] += y;
      s2[r] = fmaf(y, y, s2[r]);
    }
  }
#pragma unroll
  for (int r = 0; r < 16; ++r) {
#pragma unroll
    for (int off = 1; off < 32; off <<= 1) {
      s1[r] += __shfl_xor(s1[r], off);
      s2[r] += __shfl_xor(s2[r], off);
    }
  }
  if (cl == 0) {
#pragma unroll
    for (int r = 0; r < 16; ++r) {
      int R = (r & 3) + 8 * (r >> 2) + 4 * hi;
      red[w][R][0] = s1[r];
      red[w][R][1] = s2[r];
    }
  }
  __syncthreads();
  if (tid < 64) {
    int R = tid & 31, st = tid >> 5;
    redf[R][st] = red[0][R][st] + red[1][R][st] + red[2][R][st] + red[3][R][st];
  }
  __syncthreads();

  float gv[6], bv[6];
#pragma unroll
  for (int t = 0; t < 6; ++t) {
    int col = w * 192 + t * 32 + cl;
    gv[t] = gamma[n * 768 + col];
    bv[t] = beta[n * 768 + col];
  }
#pragma unroll
  for (int r = 0; r < 16; ++r) {
    int R = (r & 3) + 8 * (r >> 2) + 4 * hi;
    float mu = redf[R][0] * (1.0f / 768.0f);
    float var = redf[R][1] * (1.0f / 768.0f) - mu * mu;
    float rs = rsqrtf(var + LNEPS);
#pragma unroll
    for (int t = 0; t < 6; ++t) {
      int col = w * 192 + t * 32 + cl;
      out[(size_t)(row0 + R) * 768 + col] = (acc[t][r] - mu) * rs * gv[t] + bv[t];
    }
  }
}

// ---------------------------------------------------------------------------
extern "C" void kernel_launch(void* const* d_in, const int* in_sizes, int n_in,
                              void* d_out, int out_size, void* d_ws, size_t ws_size,
                              hipStream_t stream) {
  const float* x     = (const float*)d_in[0];
  const float* hist  = (const float*)d_in[1];
  const int*   mask  = (const int*)d_in[2];
  const float* Wq    = (const float*)d_in[3];
  const float* Wk    = (const float*)d_in[4];
  const float* Wv    = (const float*)d_in[5];
  const float* Wo    = (const float*)d_in[6];
  const float* gamma = (const float*)d_in[7];
  const float* beta  = (const float*)d_in[8];
  float* out = (float*)d_out;

  char* ws = (char*)d_ws;
  __hip_bfloat16* Qb  = (__hip_bfloat16*)ws;  ws += (size_t)NROW * II * 2;
  __hip_bfloat16* Kh  = (__hip_bfloat16*)ws;  ws += (size_t)NKVROW * II * 2;
  __hip_bfloat16* Vt2 = (__hip_bfloat16*)ws;  ws += (size_t)NKVROW * II * 2;
  __hip_bfloat16* Op  = (__hip_bfloat16*)ws;  ws += (size_t)NSPLIT * NROW * II * 2;
  float* Mp           = (float*)ws;           ws += (size_t)NSPLIT * 24 * 2 * TT * 4;
  float* Lp           = (float*)ws;           ws += (size_t)NSPLIT * 24 * 2 * TT * 4;
  __hip_bfloat16* Bkv = (__hip_bfloat16*)ws;  ws += (size_t)128 * 768 * 2;
  __hip_bfloat16* Bq  = (__hip_bfloat16*)ws;  ws += (size_t)NDOM * 64 * 768 * 2;
  __hip_bfloat16* Bo  = (__hip_bfloat16*)ws;  ws += (size_t)NDOM * 768 * 64 * 2;
  float* bias2        = (float*)ws;           ws += (size_t)BB * SS * 4;

  const int PREP_N = 128*768 + NDOM*64*768 + NDOM*768*64 + BB*SS;
  prep_kernel<<<(PREP_N + 255) / 256, 256, 0, stream>>>(mask, Wk, Wv, Wq, Wo, Bkv, Bq, Bo, bias2);
  qkv_gemm_kernel<<<NKVB + NQB, 256, 0, stream>>>(x, hist, Bkv, Bq, Qb, Kh, Vt2);
  attn_kernel<<<48 * 8 * NSPLIT, 256, 0, stream>>>(Qb, Kh, Vt2, bias2, Op, Mp, Lp);
  oproj_ln_kernel<<<NROW / 32, 256, 0, stream>>>(x, Op, Mp, Lp, Bo, gamma, beta, out);
}